// Round 5
// baseline (3255.087 us; speedup 1.0000x reference)
//
#include <hip/hip_runtime.h>
#include <float.h>

#define TOK   32768   // B*S
#define DM    2048    // D_MODEL
#define CO    1024    // CORE
#define MS    256     // M slots
#define NH    8       // heads
#define HDIM  128     // head dim
#define IN2   2048    // 2*CORE
#define ITR   4096    // CORE*FACTOR

typedef float4 f4;
typedef __attribute__((ext_vector_type(8))) short bf16x8;
typedef __attribute__((ext_vector_type(4))) float f32x4;

__device__ __forceinline__ unsigned short f2b(float x) {   // fp32 -> bf16 RNE
    unsigned int u = __float_as_uint(x);
    u += 0x7fff + ((u >> 16) & 1);
    return (unsigned short)(u >> 16);
}
__device__ __forceinline__ float b2f(unsigned short s) {
    return __uint_as_float(((unsigned int)s) << 16);
}

__device__ __forceinline__ void gload16(const void* g, void* l) {
    __builtin_amdgcn_global_load_lds(
        (const __attribute__((address_space(1))) unsigned int*)g,
        (__attribute__((address_space(3))) unsigned int*)l, 16, 0, 0);
}

// =====================================================================
// Unified split-bf16 MFMA GEMM, 128x128 tile, 4 waves, BK=32, 2 barriers.
// C = A @ B^T in "NT row-major" form: A rows [M][K], B rows [N][K].
// A = Ah+Al, B = Bh+Bl (bf16 splits); acc += Ah*Bh + Ah*Bl + Al*Bh.
// LDS tiles [128][32] bf16, oct-swizzled: 16B chunk at (row, oct) lives at
// chunk index oct ^ (row&3). gload_lds writes linearly -> source address is
// inverse-permuted (same involution) per rule "both sides or neither".
// MODE 0 (kv):     A = fp32 flat[32768][2048] (in-kernel split), B = WT
//                  [1024][2048]; epilogue: +bq, write kvh/kvl bf16.
// MODE 1 (scores): A = qsh/qsl[256][1024] col-slice h*128, B = kvh/kvl
//                  [32768][1024] col-slice h*128; epilogue: *scale + 5*bias,
//                  dual fp32 write.
// =====================================================================
template<int MODE>
__global__ __launch_bounds__(256) void mfma_gemm(
    const float* __restrict__ Afp,
    const unsigned short* __restrict__ Abh, const unsigned short* __restrict__ Abl,
    const unsigned short* __restrict__ Bh,  const unsigned short* __restrict__ Bl,
    int pitchA, int pitchB, int ksteps,
    const float* __restrict__ bias,
    float* __restrict__ o1, float* __restrict__ o2,
    unsigned short* __restrict__ okh, unsigned short* __restrict__ okl)
{
    __shared__ unsigned short smem[4 * 4096];   // Ah | Al | Bh | Bl, each [128][32]

    const int tid  = threadIdx.x;
    const int lane = tid & 63;
    const int wv   = tid >> 6;
    const int wm   = wv >> 1, wn = wv & 1;

    const int row0A = blockIdx.y * 128;
    const int row0B = blockIdx.x * 128;
    const int coff  = (MODE == 1) ? blockIdx.z * HDIM : 0;

    f32x4 acc[4][4];
#pragma unroll
    for (int i = 0; i < 4; ++i)
#pragma unroll
        for (int j = 0; j < 4; ++j) acc[i][j] = (f32x4){0.f, 0.f, 0.f, 0.f};

    for (int ks = 0; ks < ksteps; ++ks) {
        const int acol = coff + ks * 32;

        // ---- B tiles (both modes): global_load_lds, source-oct-permuted ----
#pragma unroll
        for (int t = 2; t < 4; ++t) {
            const unsigned short* src = (t == 2) ? Bh : Bl;
#pragma unroll
            for (int j = 0; j < 2; ++j) {
                const int c    = wv * 2 + j;
                const int grow = c * 16 + (lane >> 2);
                const int osrc = (lane & 3) ^ (grow & 3);
                gload16(src + (size_t)(row0B + grow) * pitchB + acol + osrc * 8,
                        &smem[t * 4096 + c * 512]);
            }
        }
        // ---- A tiles ----
        if (MODE == 1) {
#pragma unroll
            for (int t = 0; t < 2; ++t) {
                const unsigned short* src = (t == 0) ? Abh : Abl;
#pragma unroll
                for (int j = 0; j < 2; ++j) {
                    const int c    = wv * 2 + j;
                    const int grow = c * 16 + (lane >> 2);
                    const int osrc = (lane & 3) ^ (grow & 3);
                    gload16(src + (size_t)(row0A + grow) * pitchA + acol + osrc * 8,
                            &smem[t * 4096 + c * 512]);
                }
            }
        } else {
            // reg-stage fp32 -> split bf16, swizzled ds_write
#pragma unroll
            for (int p = 0; p < 4; ++p) {
                const int r  = p * 32 + (tid >> 3);
                const int c4 = (tid & 7) * 4;
                const f4 v = *(const f4*)(Afp + (size_t)(row0A + r) * pitchA + acol + c4);
                const unsigned short h0 = f2b(v.x), h1 = f2b(v.y), h2 = f2b(v.z), h3 = f2b(v.w);
                const unsigned short l0 = f2b(v.x - b2f(h0)), l1 = f2b(v.y - b2f(h1));
                const unsigned short l2 = f2b(v.z - b2f(h2)), l3 = f2b(v.w - b2f(h3));
                const int oct = c4 >> 3;
                const int pos = r * 32 + ((oct ^ (r & 3)) << 3) + (c4 & 4);
                ushort4 hv; hv.x = h0; hv.y = h1; hv.z = h2; hv.w = h3;
                ushort4 lv; lv.x = l0; lv.y = l1; lv.z = l2; lv.w = l3;
                *(ushort4*)&smem[pos]        = hv;
                *(ushort4*)&smem[4096 + pos] = lv;
            }
        }
        __syncthreads();   // drains vmcnt (gload_lds) + lgkmcnt (ds_write)

        // ---- fragments (swizzled read) + 48 MFMA ----
        bf16x8 ah[4], al[4], bh[4], bl[4];
#pragma unroll
        for (int f = 0; f < 4; ++f) {
            const int ra = wm * 64 + f * 16 + (lane & 15);
            const int rb = wn * 64 + f * 16 + (lane & 15);
            const int ka = (lane >> 4) ^ (ra & 3);
            const int kb = (lane >> 4) ^ (rb & 3);
            ah[f] = *(const bf16x8*)&smem[          ra * 32 + ka * 8];
            al[f] = *(const bf16x8*)&smem[1 * 4096 + ra * 32 + ka * 8];
            bh[f] = *(const bf16x8*)&smem[2 * 4096 + rb * 32 + kb * 8];
            bl[f] = *(const bf16x8*)&smem[3 * 4096 + rb * 32 + kb * 8];
        }
#pragma unroll
        for (int i = 0; i < 4; ++i)
#pragma unroll
            for (int j = 0; j < 4; ++j) {
                acc[i][j] = __builtin_amdgcn_mfma_f32_16x16x32_bf16(al[i], bh[j], acc[i][j], 0, 0, 0);
                acc[i][j] = __builtin_amdgcn_mfma_f32_16x16x32_bf16(ah[i], bl[j], acc[i][j], 0, 0, 0);
                acc[i][j] = __builtin_amdgcn_mfma_f32_16x16x32_bf16(ah[i], bh[j], acc[i][j], 0, 0, 0);
            }
        __syncthreads();   // all reads done before next overwrite
    }

    // ---- epilogue.  C/D frag: col = lane&15, row = (lane>>4)*4 + reg ----
    if (MODE == 0) {
#pragma unroll
        for (int j = 0; j < 4; ++j) {
            const int n  = row0B + wn * 64 + j * 16 + (lane & 15);
            const float bj = bias[n];
#pragma unroll
            for (int i = 0; i < 4; ++i) {
                const int m0 = row0A + wm * 64 + i * 16 + (lane >> 4) * 4;
#pragma unroll
                for (int r = 0; r < 4; ++r) {
                    const float v = acc[i][j][r] + bj;
                    const unsigned short h = f2b(v);
                    const unsigned short l = f2b(v - b2f(h));
                    okh[(size_t)(m0 + r) * CO + n] = h;
                    okl[(size_t)(m0 + r) * CO + n] = l;
                }
            }
        }
    } else {
        const int h = blockIdx.z;
        const float scale = 0.08838834764831845f; // 1/sqrt(128)
#pragma unroll
        for (int i = 0; i < 4; ++i) {
            const int m0 = row0A + wm * 64 + i * 16 + (lane >> 4) * 4;
#pragma unroll
            for (int r = 0; r < 4; ++r) {
                const float b5 = 5.0f * bias[h * MS + m0 + r];
                const size_t rowo = (size_t)(h * MS + m0 + r) * TOK;
#pragma unroll
                for (int j = 0; j < 4; ++j) {
                    const int n = row0B + wn * 64 + j * 16 + (lane & 15);
                    const float v = acc[i][j][r] * scale + b5;
                    o1[rowo + n] = v;
                    o2[rowo + n] = v;
                }
            }
        }
    }
}

// ---------------- W transpose + split: Wq[2048][1024] -> WTh/WTl[1024][2048]
__global__ __launch_bounds__(256) void wtsplit_kernel(
    const float* __restrict__ W, unsigned short* __restrict__ th,
    unsigned short* __restrict__ tl)
{
    __shared__ float t[32][33];
    const int k0 = blockIdx.y * 32, n0 = blockIdx.x * 32;
    const int r = threadIdx.x >> 5, c = threadIdx.x & 31;
#pragma unroll
    for (int p = 0; p < 4; ++p)
        t[r + p * 8][c] = W[(size_t)(k0 + r + p * 8) * CO + n0 + c];
    __syncthreads();
#pragma unroll
    for (int p = 0; p < 4; ++p) {
        const int rn = r + p * 8;                 // row within n-tile
        const float v = t[c][rn];                 // transposed read (padded)
        const unsigned short h = f2b(v);
        const size_t o = (size_t)(n0 + rn) * DM + k0 + c;
        th[o] = h;
        tl[o] = f2b(v - b2f(h));
    }
}

// ---------------- elementwise split: in fp32 -> hi/lo bf16 ----
__global__ __launch_bounds__(256) void split_kernel(
    const float* __restrict__ in, unsigned short* __restrict__ oh,
    unsigned short* __restrict__ ol, int n)
{
    const int i = blockIdx.x * 256 + threadIdx.x;
    if (i < n) {
        const float v = in[i];
        const unsigned short h = f2b(v);
        oh[i] = h;
        ol[i] = f2b(v - b2f(h));
    }
}

// ---------------- generic fp32 GEMM (small MLPs): C = act(A@B + bias) ----
template<bool RELU>
__global__ __launch_bounds__(256) void sgemm_kernel(
    const float* __restrict__ A, const float* __restrict__ B,
    const float* __restrict__ bias, float* __restrict__ C,
    int N, int K)
{
    __shared__ float As[16][64];
    __shared__ float Bs[16][64];
    const int tid = threadIdx.x;
    const int br = blockIdx.y, bc = blockIdx.x;
    const int tm = tid >> 4, tn = tid & 15;
    const int arow = tid >> 2, ac4 = (tid & 3) * 4;
    const int brow = tid >> 4, bc4 = (tid & 15) * 4;

    float acc[4][4] = {};
    const float* Aptr = A + (size_t)(br * 64 + arow) * K + ac4;
    const float* Bptr = B + (size_t)brow * N + bc * 64 + bc4;

    for (int k0 = 0; k0 < K; k0 += 16) {
        f4 a = *(const f4*)(Aptr + k0);
        f4 b = *(const f4*)(Bptr + (size_t)k0 * N);
        __syncthreads();
        As[ac4 + 0][arow] = a.x; As[ac4 + 1][arow] = a.y;
        As[ac4 + 2][arow] = a.z; As[ac4 + 3][arow] = a.w;
        *(f4*)&Bs[brow][bc4] = b;
        __syncthreads();
#pragma unroll
        for (int kk = 0; kk < 16; ++kk) {
            f4 av = *(const f4*)&As[kk][tm * 4];
            f4 bv = *(const f4*)&Bs[kk][tn * 4];
            acc[0][0] += av.x * bv.x; acc[0][1] += av.x * bv.y; acc[0][2] += av.x * bv.z; acc[0][3] += av.x * bv.w;
            acc[1][0] += av.y * bv.x; acc[1][1] += av.y * bv.y; acc[1][2] += av.y * bv.z; acc[1][3] += av.y * bv.w;
            acc[2][0] += av.z * bv.x; acc[2][1] += av.z * bv.y; acc[2][2] += av.z * bv.z; acc[2][3] += av.z * bv.w;
            acc[3][0] += av.w * bv.x; acc[3][1] += av.w * bv.y; acc[3][2] += av.w * bv.z; acc[3][3] += av.w * bv.w;
        }
    }

    const int crow0 = br * 64 + tm * 4;
    const int ccol0 = bc * 64 + tn * 4;
    f4 bvec = *(const f4*)&bias[ccol0];
#pragma unroll
    for (int i = 0; i < 4; ++i) {
        f4 v;
        v.x = acc[i][0] + bvec.x; v.y = acc[i][1] + bvec.y;
        v.z = acc[i][2] + bvec.z; v.w = acc[i][3] + bvec.w;
        if (RELU) {
            v.x = fmaxf(v.x, 0.f); v.y = fmaxf(v.y, 0.f);
            v.z = fmaxf(v.z, 0.f); v.w = fmaxf(v.w, 0.f);
        }
        *(f4*)&C[(size_t)(crow0 + i) * N + ccol0] = v;
    }
}

// ---------------- top-k over slots per (h, token) + LDS scatter ----
#define TKCHUNKS 4

__device__ __forceinline__ void ins4(float s, int m,
    float& v0, float& v1, float& v2, float& v3,
    int& i0, int& i1, int& i2, int& i3)
{
    if (s > v3) {
        if (s > v1) {
            if (s > v0) { v3=v2;i3=i2; v2=v1;i2=i1; v1=v0;i1=i0; v0=s;i0=m; }
            else        { v3=v2;i3=i2; v2=v1;i2=i1; v1=s;i1=m; }
        } else {
            if (s > v2) { v3=v2;i3=i2; v2=s;i2=m; }
            else        { v3=s;i3=m; }
        }
    }
}

__global__ __launch_bounds__(256) void topk_scatter_kernel(
    const float* __restrict__ scores,            // [8,256,32768]
    const unsigned short* __restrict__ kvh,      // [32768,1024]
    const unsigned short* __restrict__ kvl,
    float* __restrict__ attended,                // [8,256,128] (pre-zeroed)
    int* __restrict__ counts)                    // [8,256]     (pre-zeroed)
{
    extern __shared__ float accs[];              // 256*128 floats = 128 KB
    __shared__ int cnt[MS];

    const int tid = threadIdx.x;
    const int h = blockIdx.y;

    for (int i = tid; i < MS * HDIM; i += 256) accs[i] = 0.f;
    cnt[tid] = 0;
    __syncthreads();

    for (int chunk = 0; chunk < TKCHUNKS; ++chunk) {
        const int n = (blockIdx.x * TKCHUNKS + chunk) * 256 + tid;

        float v0 = -FLT_MAX, v1 = -FLT_MAX, v2 = -FLT_MAX, v3 = -FLT_MAX;
        int i0 = 0, i1 = 0, i2 = 0, i3 = 0;
        const float* sp = scores + (size_t)(h * MS) * TOK + n;
        for (int m0 = 0; m0 < MS; m0 += 8) {
            float s[8];
#pragma unroll
            for (int j = 0; j < 8; ++j) s[j] = sp[(size_t)(m0 + j) * TOK];
#pragma unroll
            for (int j = 0; j < 8; ++j) ins4(s[j], m0 + j, v0, v1, v2, v3, i0, i1, i2, i3);
        }

        const ushort4* kh4 = (const ushort4*)(kvh + (size_t)n * CO + h * HDIM);
        const ushort4* kl4 = (const ushort4*)(kvl + (size_t)n * CO + h * HDIM);
#pragma unroll 4
        for (int c = 0; c < 32; ++c) {
            const ushort4 a = kh4[c], b = kl4[c];
            f4 v;
            v.x = b2f(a.x) + b2f(b.x); v.y = b2f(a.y) + b2f(b.y);
            v.z = b2f(a.z) + b2f(b.z); v.w = b2f(a.w) + b2f(b.w);
            const int base = c * 4;
#define SCAT(slot) { \
            const int r_ = (slot) << 7; \
            atomicAdd(&accs[r_ | ((base + 0 + (slot)) & 127)], v.x); \
            atomicAdd(&accs[r_ | ((base + 1 + (slot)) & 127)], v.y); \
            atomicAdd(&accs[r_ | ((base + 2 + (slot)) & 127)], v.z); \
            atomicAdd(&accs[r_ | ((base + 3 + (slot)) & 127)], v.w); }
            SCAT(i0) SCAT(i1) SCAT(i2) SCAT(i3)
#undef SCAT
        }
        atomicAdd(&cnt[i0], 1); atomicAdd(&cnt[i1], 1);
        atomicAdd(&cnt[i2], 1); atomicAdd(&cnt[i3], 1);
    }
    __syncthreads();

    float* att = attended + (size_t)h * MS * HDIM;
    for (int i = tid; i < MS * HDIM; i += 256) {
        const int slot = i >> 7, d = i & 127;
        atomicAdd(&att[i], accs[(slot << 7) | ((d + slot) & 127)]);
    }
    atomicAdd(&counts[h * MS + tid], cnt[tid]);
}

// ---------------- block reduce helper (sum, sumsq) ----
__device__ __forceinline__ void block_reduce2(float& s, float& sq) {
    for (int o = 32; o > 0; o >>= 1) {
        s  += __shfl_down(s, o);
        sq += __shfl_down(sq, o);
    }
    __shared__ float ls[4], lsq[4];
    const int w = threadIdx.x >> 6, lane = threadIdx.x & 63;
    if (lane == 0) { ls[w] = s; lsq[w] = sq; }
    __syncthreads();
    s  = ls[0] + ls[1] + ls[2] + ls[3];
    sq = lsq[0] + lsq[1] + lsq[2] + lsq[3];
}

// ---------------- LN over concat([mem, context]) rows of 2048 ----
__global__ __launch_bounds__(256) void ln1_kernel(
    const float* __restrict__ mem, const float* __restrict__ attended,
    const float* __restrict__ g, const float* __restrict__ bb,
    float* __restrict__ h1)
{
    const int m = blockIdx.x, tid = threadIdx.x;
    float x[8];
#pragma unroll
    for (int i = 0; i < 8; ++i) {
        const int col = i * 256 + tid;
        if (col < CO) {
            x[i] = mem[(size_t)m * CO + col];
        } else {
            const int cc = col - CO;
            x[i] = attended[(size_t)((cc >> 7) * MS + m) * HDIM + (cc & 127)];
        }
    }
    float s = 0.f, sq = 0.f;
#pragma unroll
    for (int i = 0; i < 8; ++i) { s += x[i]; sq += x[i] * x[i]; }
    block_reduce2(s, sq);
    const float mu = s * (1.0f / IN2);
    const float var = sq * (1.0f / IN2) - mu * mu;
    const float rs = rsqrtf(var + 1e-5f);
#pragma unroll
    for (int i = 0; i < 8; ++i) {
        const int col = i * 256 + tid;
        h1[(size_t)m * IN2 + col] = (x[i] - mu) * rs * g[col] + bb[col];
    }
}

// ---------------- final LN over rows of 1024 -> dyn output ----
__global__ __launch_bounds__(256) void ln2_kernel(
    const float* __restrict__ in, const float* __restrict__ g,
    const float* __restrict__ bb, float* __restrict__ out)
{
    const int m = blockIdx.x, tid = threadIdx.x;
    float x[4];
#pragma unroll
    for (int i = 0; i < 4; ++i) x[i] = in[(size_t)m * CO + i * 256 + tid];
    float s = 0.f, sq = 0.f;
#pragma unroll
    for (int i = 0; i < 4; ++i) { s += x[i]; sq += x[i] * x[i]; }
    block_reduce2(s, sq);
    const float mu = s * (1.0f / CO);
    const float var = sq * (1.0f / CO) - mu * mu;
    const float rs = rsqrtf(var + 1e-5f);
#pragma unroll
    for (int i = 0; i < 4; ++i) {
        const int col = i * 256 + tid;
        out[(size_t)m * CO + col] = (x[i] - mu) * rs * g[col] + bb[col];
    }
}

// ---------------- load_fraction[m] = sum_h counts[h][m] / 8 ----
__global__ __launch_bounds__(256) void lf_kernel(
    const int* __restrict__ counts, float* __restrict__ out)
{
    const int m = threadIdx.x;
    float s = 0.f;
#pragma unroll
    for (int h = 0; h < NH; ++h) s += (float)counts[h * MS + m];
    out[m] = s * 0.125f;
}

extern "C" void kernel_launch(void* const* d_in, const int* in_sizes, int n_in,
                              void* d_out, int out_size, void* d_ws, size_t ws_size,
                              hipStream_t stream)
{
    const float* bqry = (const float*)d_in[0];   // [8,4096,2048] -> [32768][2048]
    const float* memb = (const float*)d_in[1];   // [1,256,1024]
    const float* Wq   = (const float*)d_in[2];   // [2048][1024]
    const float* bq   = (const float*)d_in[3];
    const float* Ws1  = (const float*)d_in[4];
    const float* bs1  = (const float*)d_in[5];
    const float* Ws2  = (const float*)d_in[6];
    const float* bs2  = (const float*)d_in[7];
    const float* mbia = (const float*)d_in[8];   // [8,256,1]
    const float* ln1g = (const float*)d_in[9];
    const float* ln1b = (const float*)d_in[10];
    const float* Wu1  = (const float*)d_in[11];
    const float* bu1  = (const float*)d_in[12];
    const float* Wu2  = (const float*)d_in[13];
    const float* bu2  = (const float*)d_in[14];
    const float* lnog = (const float*)d_in[15];
    const float* lnob = (const float*)d_in[16];

    float* out = (float*)d_out;
    float* dyn_out = out;                                   // 256*1024
    float* sc1 = out + (size_t)MS * CO;                     // scores_div  [8,256,32768]
    float* sc2 = sc1 + (size_t)NH * MS * TOK;               // gate_logits [8,256,32768]
    float* lf  = sc2 + (size_t)NH * MS * TOK;               // [256]

    char* wsp = (char*)d_ws;
    auto alloc = [&](size_t bytes) {
        char* p = wsp;
        wsp += (bytes + 255) & ~(size_t)255;
        return p;
    };
    unsigned short* kvh = (unsigned short*)alloc((size_t)TOK * CO * 2);   // 67 MB
    unsigned short* kvl = (unsigned short*)alloc((size_t)TOK * CO * 2);   // 67 MB
    unsigned short* WTh = (unsigned short*)alloc((size_t)CO * DM * 2);    // 4 MB
    unsigned short* WTl = (unsigned short*)alloc((size_t)CO * DM * 2);    // 4 MB
    unsigned short* qsh = (unsigned short*)alloc((size_t)MS * CO * 2);
    unsigned short* qsl = (unsigned short*)alloc((size_t)MS * CO * 2);
    float* hq  = (float*)alloc((size_t)MS * ITR * 4);
    float* qs  = (float*)alloc((size_t)MS * CO * 4);
    float* att = (float*)alloc((size_t)NH * MS * HDIM * 4);
    int*  counts = (int*)alloc((size_t)NH * MS * 4);
    float* h1  = (float*)alloc((size_t)MS * IN2 * 4);
    float* hu  = (float*)alloc((size_t)MS * IN2 * 4);
    float* h2  = (float*)alloc((size_t)MS * CO * 4);

    hipMemsetAsync(att, 0, (size_t)NH * MS * HDIM * 4, stream);
    hipMemsetAsync(counts, 0, (size_t)NH * MS * 4, stream);

    const dim3 blk(256);

    // q_slots = relu(mem@Ws1+bs1)@Ws2+bs2   (fp32, small)
    sgemm_kernel<true ><<<dim3(ITR / 64, MS / 64), blk, 0, stream>>>(memb, Ws1, bs1, hq, ITR, CO);
    sgemm_kernel<false><<<dim3(CO  / 64, MS / 64), blk, 0, stream>>>(hq,  Ws2, bs2, qs, CO, ITR);
    split_kernel<<<dim3(MS * CO / 256), blk, 0, stream>>>(qs, qsh, qsl, MS * CO);

    // W transpose + split
    wtsplit_kernel<<<dim3(CO / 32, DM / 32), blk, 0, stream>>>(Wq, WTh, WTl);

    // kv = flat@Wq+bq  via split-bf16 MFMA -> kvh/kvl
    mfma_gemm<0><<<dim3(CO / 128, TOK / 128, 1), blk, 0, stream>>>(
        bqry, nullptr, nullptr, WTh, WTl, DM, DM, DM / 32,
        bq, nullptr, nullptr, kvh, kvl);

    // scores (dual write) via split-bf16 MFMA
    mfma_gemm<1><<<dim3(TOK / 128, MS / 128, NH), blk, 0, stream>>>(
        nullptr, qsh, qsl, kvh, kvl, CO, CO, HDIM / 32,
        mbia, sc1, sc2, nullptr, nullptr);

    // top-k + scatter into attended (128KB dynamic LDS -> opt-in)
    hipFuncSetAttribute((const void*)topk_scatter_kernel,
                        hipFuncAttributeMaxDynamicSharedMemorySize, MS * HDIM * 4);
    topk_scatter_kernel<<<dim3(TOK / (256 * TKCHUNKS), NH), blk, MS * HDIM * 4, stream>>>(
        sc2, kvh, kvl, att, counts);

    // update MLP (fp32, small)
    ln1_kernel<<<dim3(MS), blk, 0, stream>>>(memb, att, ln1g, ln1b, h1);
    sgemm_kernel<true ><<<dim3(IN2 / 64, MS / 64), blk, 0, stream>>>(h1, Wu1, bu1, hu, IN2, IN2);
    sgemm_kernel<false><<<dim3(CO  / 64, MS / 64), blk, 0, stream>>>(hu, Wu2, bu2, h2, CO, IN2);
    ln2_kernel<<<dim3(MS), blk, 0, stream>>>(h2, lnog, lnob, dyn_out);

    lf_kernel<<<1, blk, 0, stream>>>(counts, lf);
}

// Round 7
// 2475.844 us; speedup vs baseline: 1.3147x; 1.3147x over previous
//
#include <hip/hip_runtime.h>
#include <float.h>

#define TOK   32768   // B*S
#define DM    2048    // D_MODEL
#define CO    1024    // CORE
#define MS    256     // M slots
#define NH    8       // heads
#define HDIM  128     // head dim
#define IN2   2048    // 2*CORE
#define ITR   4096    // CORE*FACTOR
#define SKC   32      // split-K chunks for gather_gemm

typedef float4 f4;
typedef __attribute__((ext_vector_type(8))) short bf16x8;
typedef __attribute__((ext_vector_type(4))) float f32x4;

__device__ __forceinline__ unsigned short f2b(float x) {   // fp32 -> bf16 RNE
    unsigned int u = __float_as_uint(x);
    u += 0x7fff + ((u >> 16) & 1);
    return (unsigned short)(u >> 16);
}
__device__ __forceinline__ float b2f(unsigned short s) {
    return __uint_as_float(((unsigned int)s) << 16);
}

__device__ __forceinline__ void gload16(const void* g, void* l) {
    __builtin_amdgcn_global_load_lds(
        (const __attribute__((address_space(1))) unsigned int*)g,
        (__attribute__((address_space(3))) unsigned int*)l, 16, 0, 0);
}

// =====================================================================
// Unified split-bf16 MFMA GEMM, 128x128 tile, 4 waves, BK=32, 2 barriers.
// C = A @ B^T in NT row-major form. (validated on HW in round 5)
// =====================================================================
template<int MODE>
__global__ __launch_bounds__(256) void mfma_gemm(
    const float* __restrict__ Afp,
    const unsigned short* __restrict__ Abh, const unsigned short* __restrict__ Abl,
    const unsigned short* __restrict__ Bh,  const unsigned short* __restrict__ Bl,
    int pitchA, int pitchB, int ksteps,
    const float* __restrict__ bias,
    float* __restrict__ o1, float* __restrict__ o2,
    unsigned short* __restrict__ okh, unsigned short* __restrict__ okl)
{
    __shared__ unsigned short smem[4 * 4096];   // Ah | Al | Bh | Bl, each [128][32]

    const int tid  = threadIdx.x;
    const int lane = tid & 63;
    const int wv   = tid >> 6;
    const int wm   = wv >> 1, wn = wv & 1;

    const int row0A = blockIdx.y * 128;
    const int row0B = blockIdx.x * 128;
    const int coff  = (MODE == 1) ? blockIdx.z * HDIM : 0;

    f32x4 acc[4][4];
#pragma unroll
    for (int i = 0; i < 4; ++i)
#pragma unroll
        for (int j = 0; j < 4; ++j) acc[i][j] = (f32x4){0.f, 0.f, 0.f, 0.f};

    for (int ks = 0; ks < ksteps; ++ks) {
        const int acol = coff + ks * 32;

#pragma unroll
        for (int t = 2; t < 4; ++t) {
            const unsigned short* src = (t == 2) ? Bh : Bl;
#pragma unroll
            for (int j = 0; j < 2; ++j) {
                const int c    = wv * 2 + j;
                const int grow = c * 16 + (lane >> 2);
                const int osrc = (lane & 3) ^ (grow & 3);
                gload16(src + (size_t)(row0B + grow) * pitchB + acol + osrc * 8,
                        &smem[t * 4096 + c * 512]);
            }
        }
        if (MODE == 1) {
#pragma unroll
            for (int t = 0; t < 2; ++t) {
                const unsigned short* src = (t == 0) ? Abh : Abl;
#pragma unroll
                for (int j = 0; j < 2; ++j) {
                    const int c    = wv * 2 + j;
                    const int grow = c * 16 + (lane >> 2);
                    const int osrc = (lane & 3) ^ (grow & 3);
                    gload16(src + (size_t)(row0A + grow) * pitchA + acol + osrc * 8,
                            &smem[t * 4096 + c * 512]);
                }
            }
        } else {
#pragma unroll
            for (int p = 0; p < 4; ++p) {
                const int r  = p * 32 + (tid >> 3);
                const int c4 = (tid & 7) * 4;
                const f4 v = *(const f4*)(Afp + (size_t)(row0A + r) * pitchA + acol + c4);
                const unsigned short h0 = f2b(v.x), h1 = f2b(v.y), h2 = f2b(v.z), h3 = f2b(v.w);
                const unsigned short l0 = f2b(v.x - b2f(h0)), l1 = f2b(v.y - b2f(h1));
                const unsigned short l2 = f2b(v.z - b2f(h2)), l3 = f2b(v.w - b2f(h3));
                const int oct = c4 >> 3;
                const int pos = r * 32 + ((oct ^ (r & 3)) << 3) + (c4 & 4);
                ushort4 hv; hv.x = h0; hv.y = h1; hv.z = h2; hv.w = h3;
                ushort4 lv; lv.x = l0; lv.y = l1; lv.z = l2; lv.w = l3;
                *(ushort4*)&smem[pos]        = hv;
                *(ushort4*)&smem[4096 + pos] = lv;
            }
        }
        __syncthreads();

        bf16x8 ah[4], al[4], bh[4], bl[4];
#pragma unroll
        for (int f = 0; f < 4; ++f) {
            const int ra = wm * 64 + f * 16 + (lane & 15);
            const int rb = wn * 64 + f * 16 + (lane & 15);
            const int ka = (lane >> 4) ^ (ra & 3);
            const int kb = (lane >> 4) ^ (rb & 3);
            ah[f] = *(const bf16x8*)&smem[          ra * 32 + ka * 8];
            al[f] = *(const bf16x8*)&smem[1 * 4096 + ra * 32 + ka * 8];
            bh[f] = *(const bf16x8*)&smem[2 * 4096 + rb * 32 + kb * 8];
            bl[f] = *(const bf16x8*)&smem[3 * 4096 + rb * 32 + kb * 8];
        }
#pragma unroll
        for (int i = 0; i < 4; ++i)
#pragma unroll
            for (int j = 0; j < 4; ++j) {
                acc[i][j] = __builtin_amdgcn_mfma_f32_16x16x32_bf16(al[i], bh[j], acc[i][j], 0, 0, 0);
                acc[i][j] = __builtin_amdgcn_mfma_f32_16x16x32_bf16(ah[i], bl[j], acc[i][j], 0, 0, 0);
                acc[i][j] = __builtin_amdgcn_mfma_f32_16x16x32_bf16(ah[i], bh[j], acc[i][j], 0, 0, 0);
            }
        __syncthreads();
    }

    if (MODE == 0) {
#pragma unroll
        for (int j = 0; j < 4; ++j) {
            const int n  = row0B + wn * 64 + j * 16 + (lane & 15);
            const float bj = bias[n];
#pragma unroll
            for (int i = 0; i < 4; ++i) {
                const int m0 = row0A + wm * 64 + i * 16 + (lane >> 4) * 4;
#pragma unroll
                for (int r = 0; r < 4; ++r) {
                    const float v = acc[i][j][r] + bj;
                    const unsigned short h = f2b(v);
                    const unsigned short l = f2b(v - b2f(h));
                    okh[(size_t)(m0 + r) * CO + n] = h;
                    okl[(size_t)(m0 + r) * CO + n] = l;
                }
            }
        }
    } else {
        const int h = blockIdx.z;
        const float scale = 0.08838834764831845f; // 1/sqrt(128)
#pragma unroll
        for (int i = 0; i < 4; ++i) {
            const int m0 = row0A + wm * 64 + i * 16 + (lane >> 4) * 4;
#pragma unroll
            for (int r = 0; r < 4; ++r) {
                const float b5 = 5.0f * bias[h * MS + m0 + r];
                const size_t rowo = (size_t)(h * MS + m0 + r) * TOK;
#pragma unroll
                for (int j = 0; j < 4; ++j) {
                    const int n = row0B + wn * 64 + j * 16 + (lane & 15);
                    const float v = acc[i][j][r] * scale + b5;
                    o1[rowo + n] = v;
                    o2[rowo + n] = v;
                }
            }
        }
    }
}

// ---------------- W transpose + split: Wq[2048][1024] -> WTh/WTl[1024][2048]
__global__ __launch_bounds__(256) void wtsplit_kernel(
    const float* __restrict__ W, unsigned short* __restrict__ th,
    unsigned short* __restrict__ tl)
{
    __shared__ float t[32][33];
    const int k0 = blockIdx.y * 32, n0 = blockIdx.x * 32;
    const int r = threadIdx.x >> 5, c = threadIdx.x & 31;
#pragma unroll
    for (int p = 0; p < 4; ++p)
        t[r + p * 8][c] = W[(size_t)(k0 + r + p * 8) * CO + n0 + c];
    __syncthreads();
#pragma unroll
    for (int p = 0; p < 4; ++p) {
        const int rn = r + p * 8;
        const float v = t[c][rn];
        const unsigned short h = f2b(v);
        const size_t o = (size_t)(n0 + rn) * DM + k0 + c;
        th[o] = h;
        tl[o] = f2b(v - b2f(h));
    }
}

// ---------------- elementwise split: fp32 -> hi/lo bf16 ----
__global__ __launch_bounds__(256) void split_kernel(
    const float* __restrict__ in, unsigned short* __restrict__ oh,
    unsigned short* __restrict__ ol, int n)
{
    const int i = blockIdx.x * 256 + threadIdx.x;
    if (i < n) {
        const float v = in[i];
        const unsigned short h = f2b(v);
        oh[i] = h;
        ol[i] = f2b(v - b2f(h));
    }
}

// ---------------- generic fp32 GEMM (small MLPs) ----
template<bool RELU>
__global__ __launch_bounds__(256) void sgemm_kernel(
    const float* __restrict__ A, const float* __restrict__ B,
    const float* __restrict__ bias, float* __restrict__ C,
    int N, int K)
{
    __shared__ float As[16][64];
    __shared__ float Bs[16][64];
    const int tid = threadIdx.x;
    const int br = blockIdx.y, bc = blockIdx.x;
    const int tm = tid >> 4, tn = tid & 15;
    const int arow = tid >> 2, ac4 = (tid & 3) * 4;
    const int brow = tid >> 4, bc4 = (tid & 15) * 4;

    float acc[4][4] = {};
    const float* Aptr = A + (size_t)(br * 64 + arow) * K + ac4;
    const float* Bptr = B + (size_t)brow * N + bc * 64 + bc4;

    for (int k0 = 0; k0 < K; k0 += 16) {
        f4 a = *(const f4*)(Aptr + k0);
        f4 b = *(const f4*)(Bptr + (size_t)k0 * N);
        __syncthreads();
        As[ac4 + 0][arow] = a.x; As[ac4 + 1][arow] = a.y;
        As[ac4 + 2][arow] = a.z; As[ac4 + 3][arow] = a.w;
        *(f4*)&Bs[brow][bc4] = b;
        __syncthreads();
#pragma unroll
        for (int kk = 0; kk < 16; ++kk) {
            f4 av = *(const f4*)&As[kk][tm * 4];
            f4 bv = *(const f4*)&Bs[kk][tn * 4];
            acc[0][0] += av.x * bv.x; acc[0][1] += av.x * bv.y; acc[0][2] += av.x * bv.z; acc[0][3] += av.x * bv.w;
            acc[1][0] += av.y * bv.x; acc[1][1] += av.y * bv.y; acc[1][2] += av.y * bv.z; acc[1][3] += av.y * bv.w;
            acc[2][0] += av.z * bv.x; acc[2][1] += av.z * bv.y; acc[2][2] += av.z * bv.z; acc[2][3] += av.z * bv.w;
            acc[3][0] += av.w * bv.x; acc[3][1] += av.w * bv.y; acc[3][2] += av.w * bv.z; acc[3][3] += av.w * bv.w;
        }
    }

    const int crow0 = br * 64 + tm * 4;
    const int ccol0 = bc * 64 + tn * 4;
    f4 bvec = *(const f4*)&bias[ccol0];
#pragma unroll
    for (int i = 0; i < 4; ++i) {
        f4 v;
        v.x = acc[i][0] + bvec.x; v.y = acc[i][1] + bvec.y;
        v.z = acc[i][2] + bvec.z; v.w = acc[i][3] + bvec.w;
        if (RELU) {
            v.x = fmaxf(v.x, 0.f); v.y = fmaxf(v.y, 0.f);
            v.z = fmaxf(v.z, 0.f); v.w = fmaxf(v.w, 0.f);
        }
        *(f4*)&C[(size_t)(crow0 + i) * N + ccol0] = v;
    }
}

// ---------------- top-k -> bf16 gating matrix (high-occupancy, no big LDS) ----
__device__ __forceinline__ void ins4(float s, int m,
    float& v0, float& v1, float& v2, float& v3,
    int& i0, int& i1, int& i2, int& i3)
{
    if (s > v3) {
        if (s > v1) {
            if (s > v0) { v3=v2;i3=i2; v2=v1;i2=i1; v1=v0;i1=i0; v0=s;i0=m; }
            else        { v3=v2;i3=i2; v2=v1;i2=i1; v1=s;i1=m; }
        } else {
            if (s > v2) { v3=v2;i3=i2; v2=s;i2=m; }
            else        { v3=s;i3=m; }
        }
    }
}

__global__ __launch_bounds__(256) void topk_gating_kernel(
    const float* __restrict__ scores,        // [8,256,32768]
    unsigned short* __restrict__ gating,     // [8*256][32768] bf16, pre-zeroed
    int* __restrict__ counts)                // [8,256] (pre-zeroed)
{
    __shared__ int cnt[MS];
    const int tid = threadIdx.x;
    const int h = blockIdx.y;
    const int n = blockIdx.x * 256 + tid;

    cnt[tid] = 0;
    __syncthreads();

    float v0 = -FLT_MAX, v1 = -FLT_MAX, v2 = -FLT_MAX, v3 = -FLT_MAX;
    int i0 = 0, i1 = 0, i2 = 0, i3 = 0;
    const float* sp = scores + (size_t)(h * MS) * TOK + n;
    for (int m0 = 0; m0 < MS; m0 += 8) {
        float s[8];
#pragma unroll
        for (int j = 0; j < 8; ++j) s[j] = sp[(size_t)(m0 + j) * TOK];
#pragma unroll
        for (int j = 0; j < 8; ++j) ins4(s[j], m0 + j, v0, v1, v2, v3, i0, i1, i2, i3);
    }

    const size_t gb = (size_t)(h * MS) * TOK + n;
    gating[gb + (size_t)i0 * TOK] = 0x3F80;   // bf16 1.0
    gating[gb + (size_t)i1 * TOK] = 0x3F80;
    gating[gb + (size_t)i2 * TOK] = 0x3F80;
    gating[gb + (size_t)i3 * TOK] = 0x3F80;

    atomicAdd(&cnt[i0], 1); atomicAdd(&cnt[i1], 1);
    atomicAdd(&cnt[i2], 1); atomicAdd(&cnt[i3], 1);
    __syncthreads();
    atomicAdd(&counts[h * MS + tid], cnt[tid]);
}

// ---------------- kv transpose: kvh/kvl [TOK][CO] -> kvTh/kvTl [CO][TOK] ----
__global__ __launch_bounds__(256) void kvt_kernel(
    const unsigned short* __restrict__ sh, const unsigned short* __restrict__ sl,
    unsigned short* __restrict__ dh, unsigned short* __restrict__ dl)
{
    __shared__ unsigned short t[64][68];   // pad 4 shorts
    const int n0 = blockIdx.x * 64;
    const int c0 = blockIdx.y * 64;
    const int r = threadIdx.x >> 4;          // 0..15
    const int c4 = (threadIdx.x & 15) * 4;   // 0..60

#pragma unroll
    for (int pass = 0; pass < 2; ++pass) {
        const unsigned short* s = pass ? sl : sh;
        unsigned short* d = pass ? dl : dh;
        if (pass) __syncthreads();
#pragma unroll
        for (int p = 0; p < 4; ++p)
            *(ushort4*)&t[p * 16 + r][c4] =
                *(const ushort4*)&s[(size_t)(n0 + p * 16 + r) * CO + c0 + c4];
        __syncthreads();
#pragma unroll
        for (int p = 0; p < 4; ++p) {
            const int cc = p * 16 + r;
            ushort4 v;
            v.x = t[c4 + 0][cc]; v.y = t[c4 + 1][cc];
            v.z = t[c4 + 2][cc]; v.w = t[c4 + 3][cc];
            *(ushort4*)&d[(size_t)(c0 + cc) * TOK + n0 + c4] = v;
        }
    }
}

// ---------------- attended = gating @ kvT^T via MFMA, split-K ----
__global__ __launch_bounds__(256) void gather_gemm(
    const unsigned short* __restrict__ G,
    const unsigned short* __restrict__ BTh, const unsigned short* __restrict__ BTl,
    float* __restrict__ part)               // [SKC][8][256][128]
{
    __shared__ unsigned short smem[3 * 4096];   // Ag | Bh | Bl, each [128][32]
    const int tid = threadIdx.x, lane = tid & 63, wv = tid >> 6;
    const int wm = wv >> 1, wn = wv & 1;
    const int kc = blockIdx.x;
    const int mb = blockIdx.y;
    const int h  = blockIdx.z;
    const int row0A = h * MS + mb * 128;
    const int row0B = h * HDIM;
    const int k0 = kc * (TOK / SKC);

    f32x4 acc[4][4];
#pragma unroll
    for (int i = 0; i < 4; ++i)
#pragma unroll
        for (int j = 0; j < 4; ++j) acc[i][j] = (f32x4){0.f, 0.f, 0.f, 0.f};

    for (int ks = 0; ks < (TOK / SKC) / 32; ++ks) {
        const int acol = k0 + ks * 32;
#pragma unroll
        for (int j = 0; j < 2; ++j) {
            const int c    = wv * 2 + j;
            const int grow = c * 16 + (lane >> 2);
            const int osrc = (lane & 3) ^ (grow & 3);
            gload16(G + (size_t)(row0A + grow) * TOK + acol + osrc * 8,
                    &smem[c * 512]);
        }
#pragma unroll
        for (int t = 1; t < 3; ++t) {
            const unsigned short* src = (t == 1) ? BTh : BTl;
#pragma unroll
            for (int j = 0; j < 2; ++j) {
                const int c    = wv * 2 + j;
                const int grow = c * 16 + (lane >> 2);
                const int osrc = (lane & 3) ^ (grow & 3);
                gload16(src + (size_t)(row0B + grow) * TOK + acol + osrc * 8,
                        &smem[t * 4096 + c * 512]);
            }
        }
        __syncthreads();

        bf16x8 ag[4], bh[4], bl[4];
#pragma unroll
        for (int f = 0; f < 4; ++f) {
            const int ra = wm * 64 + f * 16 + (lane & 15);
            const int rb = wn * 64 + f * 16 + (lane & 15);
            const int ka = (lane >> 4) ^ (ra & 3);
            const int kb = (lane >> 4) ^ (rb & 3);
            ag[f] = *(const bf16x8*)&smem[          ra * 32 + ka * 8];
            bh[f] = *(const bf16x8*)&smem[1 * 4096 + rb * 32 + kb * 8];
            bl[f] = *(const bf16x8*)&smem[2 * 4096 + rb * 32 + kb * 8];
        }
#pragma unroll
        for (int i = 0; i < 4; ++i)
#pragma unroll
            for (int j = 0; j < 4; ++j) {
                acc[i][j] = __builtin_amdgcn_mfma_f32_16x16x32_bf16(ag[i], bh[j], acc[i][j], 0, 0, 0);
                acc[i][j] = __builtin_amdgcn_mfma_f32_16x16x32_bf16(ag[i], bl[j], acc[i][j], 0, 0, 0);
            }
        __syncthreads();
    }

    const size_t base = ((size_t)kc * NH + h) * MS;
#pragma unroll
    for (int i = 0; i < 4; ++i) {
        const int ml0 = mb * 128 + wm * 64 + i * 16 + (lane >> 4) * 4;
#pragma unroll
        for (int r = 0; r < 4; ++r) {
            const size_t rowo = (base + ml0 + r) * HDIM;
#pragma unroll
            for (int j = 0; j < 4; ++j) {
                const int d = wn * 64 + j * 16 + (lane & 15);
                part[rowo + d] = acc[i][j][r];
            }
        }
    }
}

// ---------------- reduce split-K partials -> attended ----
__global__ __launch_bounds__(256) void red_kernel(
    const float* __restrict__ part, float* __restrict__ att)
{
    const int o = blockIdx.x * 256 + threadIdx.x;
    const int stride = NH * MS * HDIM;
    float s = 0.f;
#pragma unroll
    for (int k = 0; k < SKC; ++k) s += part[(size_t)k * stride + o];
    att[o] = s;
}

// ---------------- block reduce helper (sum, sumsq) ----
__device__ __forceinline__ void block_reduce2(float& s, float& sq) {
    for (int o = 32; o > 0; o >>= 1) {
        s  += __shfl_down(s, o);
        sq += __shfl_down(sq, o);
    }
    __shared__ float ls[4], lsq[4];
    const int w = threadIdx.x >> 6, lane = threadIdx.x & 63;
    if (lane == 0) { ls[w] = s; lsq[w] = sq; }
    __syncthreads();
    s  = ls[0] + ls[1] + ls[2] + ls[3];
    sq = lsq[0] + lsq[1] + lsq[2] + lsq[3];
}

// ---------------- LN over concat([mem, context]) rows of 2048 ----
__global__ __launch_bounds__(256) void ln1_kernel(
    const float* __restrict__ mem, const float* __restrict__ attended,
    const float* __restrict__ g, const float* __restrict__ bb,
    float* __restrict__ h1)
{
    const int m = blockIdx.x, tid = threadIdx.x;
    float x[8];
#pragma unroll
    for (int i = 0; i < 8; ++i) {
        const int col = i * 256 + tid;
        if (col < CO) {
            x[i] = mem[(size_t)m * CO + col];
        } else {
            const int cc = col - CO;
            x[i] = attended[(size_t)((cc >> 7) * MS + m) * HDIM + (cc & 127)];
        }
    }
    float s = 0.f, sq = 0.f;
#pragma unroll
    for (int i = 0; i < 8; ++i) { s += x[i]; sq += x[i] * x[i]; }
    block_reduce2(s, sq);
    const float mu = s * (1.0f / IN2);
    const float var = sq * (1.0f / IN2) - mu * mu;
    const float rs = rsqrtf(var + 1e-5f);
#pragma unroll
    for (int i = 0; i < 8; ++i) {
        const int col = i * 256 + tid;
        h1[(size_t)m * IN2 + col] = (x[i] - mu) * rs * g[col] + bb[col];
    }
}

// ---------------- final LN over rows of 1024 -> dyn output ----
__global__ __launch_bounds__(256) void ln2_kernel(
    const float* __restrict__ in, const float* __restrict__ g,
    const float* __restrict__ bb, float* __restrict__ out)
{
    const int m = blockIdx.x, tid = threadIdx.x;
    float x[4];
#pragma unroll
    for (int i = 0; i < 4; ++i) x[i] = in[(size_t)m * CO + i * 256 + tid];
    float s = 0.f, sq = 0.f;
#pragma unroll
    for (int i = 0; i < 4; ++i) { s += x[i]; sq += x[i] * x[i]; }
    block_reduce2(s, sq);
    const float mu = s * (1.0f / CO);
    const float var = sq * (1.0f / CO) - mu * mu;
    const float rs = rsqrtf(var + 1e-5f);
#pragma unroll
    for (int i = 0; i < 4; ++i) {
        const int col = i * 256 + tid;
        out[(size_t)m * CO + col] = (x[i] - mu) * rs * g[col] + bb[col];
    }
}

// ---------------- load_fraction[m] = sum_h counts[h][m] / 8 ----
__global__ __launch_bounds__(256) void lf_kernel(
    const int* __restrict__ counts, float* __restrict__ out)
{
    const int m = threadIdx.x;
    float s = 0.f;
#pragma unroll
    for (int h = 0; h < NH; ++h) s += (float)counts[h * MS + m];
    out[m] = s * 0.125f;
}

extern "C" void kernel_launch(void* const* d_in, const int* in_sizes, int n_in,
                              void* d_out, int out_size, void* d_ws, size_t ws_size,
                              hipStream_t stream)
{
    const float* bqry = (const float*)d_in[0];   // [8,4096,2048] -> [32768][2048]
    const float* memb = (const float*)d_in[1];   // [1,256,1024]
    const float* Wq   = (const float*)d_in[2];   // [2048][1024]
    const float* bq   = (const float*)d_in[3];
    const float* Ws1  = (const float*)d_in[4];
    const float* bs1  = (const float*)d_in[5];
    const float* Ws2  = (const float*)d_in[6];
    const float* bs2  = (const float*)d_in[7];
    const float* mbia = (const float*)d_in[8];   // [8,256,1]
    const float* ln1g = (const float*)d_in[9];
    const float* ln1b = (const float*)d_in[10];
    const float* Wu1  = (const float*)d_in[11];
    const float* bu1  = (const float*)d_in[12];
    const float* Wu2  = (const float*)d_in[13];
    const float* bu2  = (const float*)d_in[14];
    const float* lnog = (const float*)d_in[15];
    const float* lnob = (const float*)d_in[16];

    float* out = (float*)d_out;
    float* dyn_out = out;                                   // 256*1024
    float* sc1 = out + (size_t)MS * CO;                     // scores_div  [8,256,32768]
    float* sc2 = sc1 + (size_t)NH * MS * TOK;               // gate_logits [8,256,32768]
    float* lf  = sc2 + (size_t)NH * MS * TOK;               // [256]

    char* wsp = (char*)d_ws;
    auto alloc = [&](size_t bytes) {
        char* p = wsp;
        wsp += (bytes + 255) & ~(size_t)255;
        return p;
    };
    unsigned short* kvh  = (unsigned short*)alloc((size_t)TOK * CO * 2);   // 67 MB
    unsigned short* kvl  = (unsigned short*)alloc((size_t)TOK * CO * 2);   // 67 MB
    unsigned short* kvTh = (unsigned short*)alloc((size_t)CO * TOK * 2);   // 67 MB
    unsigned short* kvTl = (unsigned short*)alloc((size_t)CO * TOK * 2);   // 67 MB
    unsigned short* gat  = (unsigned short*)alloc((size_t)NH * MS * TOK * 2); // 134 MB
    float* part = (float*)alloc((size_t)SKC * NH * MS * HDIM * 4);         // 34 MB
    unsigned short* WTh = (unsigned short*)alloc((size_t)CO * DM * 2);
    unsigned short* WTl = (unsigned short*)alloc((size_t)CO * DM * 2);
    unsigned short* qsh = (unsigned short*)alloc((size_t)MS * CO * 2);
    unsigned short* qsl = (unsigned short*)alloc((size_t)MS * CO * 2);
    float* hq  = (float*)alloc((size_t)MS * ITR * 4);
    float* qs  = (float*)alloc((size_t)MS * CO * 4);
    float* att = (float*)alloc((size_t)NH * MS * HDIM * 4);
    int*  counts = (int*)alloc((size_t)NH * MS * 4);
    float* h1  = (float*)alloc((size_t)MS * IN2 * 4);
    float* hu  = (float*)alloc((size_t)MS * IN2 * 4);
    float* h2  = (float*)alloc((size_t)MS * CO * 4);

    hipMemsetAsync(gat, 0, (size_t)NH * MS * TOK * 2, stream);
    hipMemsetAsync(counts, 0, (size_t)NH * MS * 4, stream);

    const dim3 blk(256);

    // q_slots = relu(mem@Ws1+bs1)@Ws2+bs2   (fp32, small)
    sgemm_kernel<true ><<<dim3(ITR / 64, MS / 64), blk, 0, stream>>>(memb, Ws1, bs1, hq, ITR, CO);
    sgemm_kernel<false><<<dim3(CO  / 64, MS / 64), blk, 0, stream>>>(hq,  Ws2, bs2, qs, CO, ITR);
    split_kernel<<<dim3(MS * CO / 256), blk, 0, stream>>>(qs, qsh, qsl, MS * CO);

    // W transpose + split
    wtsplit_kernel<<<dim3(CO / 32, DM / 32), blk, 0, stream>>>(Wq, WTh, WTl);

    // kv = flat@Wq+bq  via split-bf16 MFMA -> kvh/kvl
    mfma_gemm<0><<<dim3(CO / 128, TOK / 128, 1), blk, 0, stream>>>(
        bqry, nullptr, nullptr, WTh, WTl, DM, DM, DM / 32,
        bq, nullptr, nullptr, kvh, kvl);

    // kv transpose for the gather GEMM
    kvt_kernel<<<dim3(TOK / 64, CO / 64), blk, 0, stream>>>(kvh, kvl, kvTh, kvTl);

    // scores (dual write) via split-bf16 MFMA
    mfma_gemm<1><<<dim3(TOK / 128, MS / 128, NH), blk, 0, stream>>>(
        nullptr, qsh, qsl, kvh, kvl, CO, CO, HDIM / 32,
        mbia, sc1, sc2, nullptr, nullptr);

    // top-k -> gating matrix + counts
    topk_gating_kernel<<<dim3(TOK / 256, NH), blk, 0, stream>>>(sc2, gat, counts);

    // attended = gating @ kv  (dense MFMA, split-K) -> partials -> reduce
    gather_gemm<<<dim3(SKC, 2, NH), blk, 0, stream>>>(gat, kvTh, kvTl, part);
    red_kernel<<<dim3(NH * MS * HDIM / 256), blk, 0, stream>>>(part, att);

    // update MLP (fp32, small)
    ln1_kernel<<<dim3(MS), blk, 0, stream>>>(memb, att, ln1g, ln1b, h1);
    sgemm_kernel<true ><<<dim3(IN2 / 64, MS / 64), blk, 0, stream>>>(h1, Wu1, bu1, hu, IN2, IN2);
    sgemm_kernel<false><<<dim3(CO  / 64, MS / 64), blk, 0, stream>>>(hu, Wu2, bu2, h2, CO, IN2);
    ln2_kernel<<<dim3(MS), blk, 0, stream>>>(h2, lnog, lnob, dyn_out);

    lf_kernel<<<1, blk, 0, stream>>>(counts, lf);
}

// Round 8
// 2068.181 us; speedup vs baseline: 1.5739x; 1.1971x over previous
//
#include <hip/hip_runtime.h>
#include <float.h>

#define TOK   32768   // B*S
#define DM    2048    // D_MODEL
#define CO    1024    // CORE
#define MS    256     // M slots
#define NH    8       // heads
#define HDIM  128     // head dim
#define IN2   2048    // 2*CORE
#define ITR   4096    // CORE*FACTOR
#define SKC   32      // split-K chunks for gather_gemm

typedef float4 f4;
typedef __attribute__((ext_vector_type(8))) short bf16x8;
typedef __attribute__((ext_vector_type(4))) float f32x4;

__device__ __forceinline__ unsigned short f2b(float x) {   // fp32 -> bf16 RNE
    unsigned int u = __float_as_uint(x);
    u += 0x7fff + ((u >> 16) & 1);
    return (unsigned short)(u >> 16);
}
__device__ __forceinline__ float b2f(unsigned short s) {
    return __uint_as_float(((unsigned int)s) << 16);
}

__device__ __forceinline__ void gload16(const void* g, void* l) {
    __builtin_amdgcn_global_load_lds(
        (const __attribute__((address_space(1))) unsigned int*)g,
        (__attribute__((address_space(3))) unsigned int*)l, 16, 0, 0);
}

// =====================================================================
// Split-bf16 MFMA GEMM, 128x128 tile, 4 waves, BK=64, 2 barriers/K-step.
// C = A @ B^T (NT row-major: A[M][K], B[N][K]), A=Ah+Al, B=Bh+Bl,
// acc += Ah*Bh + Ah*Bl + Al*Bh.  All four tiles staged via global_load_lds.
// LDS tile = [128 rows][64 bf16] (row = 128 B = exactly 32 banks), 16B-chunk
// swizzle: position p holds source k-oct p ^ (row&7)  -> fragment reads are
// bank-uniform even per 8-lane phase. Source address pre-permuted (same
// involution) since gload_lds writes linearly (lane*16B).
// EPI: 0 = +bias, split-bf16 out | 1 = scores (scale + 5*rowbias, dual fp32)
//      2 = +bias, relu, split out | 3 = +bias, fp32 out
// KVSWZ: XCD-grouping for the kv GEMM (nbx=8, nby=256): blocks sharing an
// A row-strip land on one XCD -> A fetched once per strip.
// =====================================================================
template<int EPI, bool KVSWZ>
__global__ __launch_bounds__(256) void mfma64(
    const unsigned short* __restrict__ Abh, const unsigned short* __restrict__ Abl,
    const unsigned short* __restrict__ Bh,  const unsigned short* __restrict__ Bl,
    int pitchA, int pitchB, int pitchO, int ksteps, int coffMul,
    const float* __restrict__ bias,
    float* __restrict__ o1, float* __restrict__ o2,
    unsigned short* __restrict__ okh, unsigned short* __restrict__ okl)
{
    __shared__ unsigned short smem[4 * 8192];   // Ah|Al|Bh|Bl, each [128][64]

    const int tid  = threadIdx.x;
    const int lane = tid & 63;
    const int wv   = tid >> 6;
    const int wm   = wv >> 1, wn = wv & 1;

    int bx, by;
    if (KVSWZ) {
        const int b = blockIdx.x;           // grid = 2048, nbx=8
        const int xcd = b & 7;
        const int t = b >> 3;
        bx = t & 7;
        by = (t >> 3) * 8 + xcd;
    } else {
        bx = blockIdx.x; by = blockIdx.y;
    }
    const int row0A = by * 128;
    const int row0B = bx * 128;
    const int coff  = coffMul * blockIdx.z;

    f32x4 acc[4][4];
#pragma unroll
    for (int i = 0; i < 4; ++i)
#pragma unroll
        for (int j = 0; j < 4; ++j) acc[i][j] = (f32x4){0.f, 0.f, 0.f, 0.f};

    for (int ks = 0; ks < ksteps; ++ks) {
        const int acol = coff + ks * 64;
#pragma unroll
        for (int j = 0; j < 4; ++j) {
            const int c    = wv * 4 + j;            // chunk: 8 rows x 64 cols
            const int grow = c * 8 + (lane >> 3);
            const int osrc = (lane & 7) ^ (grow & 7);
            const size_t ga = (size_t)(row0A + grow) * pitchA + acol + osrc * 8;
            const size_t gb = (size_t)(row0B + grow) * pitchB + acol + osrc * 8;
            gload16(Abh + ga, &smem[0 * 8192 + c * 512]);
            gload16(Abl + ga, &smem[1 * 8192 + c * 512]);
            gload16(Bh  + gb, &smem[2 * 8192 + c * 512]);
            gload16(Bl  + gb, &smem[3 * 8192 + c * 512]);
        }
        __syncthreads();   // drains vmcnt (gload_lds writes landed)

#pragma unroll
        for (int s = 0; s < 2; ++s) {          // two 32-k sub-steps
            bf16x8 ah[4], al[4], bh[4], bl[4];
#pragma unroll
            for (int f = 0; f < 4; ++f) {
                const int ra = wm * 64 + f * 16 + (lane & 15);
                const int rb = wn * 64 + f * 16 + (lane & 15);
                const int ka = s * 4 + (lane >> 4);
                const int oa = ka ^ (ra & 7);
                const int ob = ka ^ (rb & 7);
                ah[f] = *(const bf16x8*)&smem[0 * 8192 + ra * 64 + oa * 8];
                al[f] = *(const bf16x8*)&smem[1 * 8192 + ra * 64 + oa * 8];
                bh[f] = *(const bf16x8*)&smem[2 * 8192 + rb * 64 + ob * 8];
                bl[f] = *(const bf16x8*)&smem[3 * 8192 + rb * 64 + ob * 8];
            }
#pragma unroll
            for (int i = 0; i < 4; ++i)
#pragma unroll
                for (int j = 0; j < 4; ++j) {
                    acc[i][j] = __builtin_amdgcn_mfma_f32_16x16x32_bf16(al[i], bh[j], acc[i][j], 0, 0, 0);
                    acc[i][j] = __builtin_amdgcn_mfma_f32_16x16x32_bf16(ah[i], bl[j], acc[i][j], 0, 0, 0);
                    acc[i][j] = __builtin_amdgcn_mfma_f32_16x16x32_bf16(ah[i], bh[j], acc[i][j], 0, 0, 0);
                }
        }
        __syncthreads();   // reads done before next overwrite
    }

    // epilogue. C/D frag: col = lane&15, row = (lane>>4)*4 + reg
    if (EPI == 1) {
        const int h = blockIdx.z;
        const float scale = 0.08838834764831845f; // 1/sqrt(128)
#pragma unroll
        for (int i = 0; i < 4; ++i) {
            const int m0 = row0A + wm * 64 + i * 16 + (lane >> 4) * 4;
#pragma unroll
            for (int r = 0; r < 4; ++r) {
                const float b5 = 5.0f * bias[h * MS + m0 + r];
                const size_t rowo = (size_t)(h * MS + m0 + r) * TOK;
#pragma unroll
                for (int j = 0; j < 4; ++j) {
                    const int n = row0B + wn * 64 + j * 16 + (lane & 15);
                    const float v = acc[i][j][r] * scale + b5;
                    o1[rowo + n] = v;
                    o2[rowo + n] = v;
                }
            }
        }
    } else {
#pragma unroll
        for (int j = 0; j < 4; ++j) {
            const int n  = row0B + wn * 64 + j * 16 + (lane & 15);
            const float bj = bias[n];
#pragma unroll
            for (int i = 0; i < 4; ++i) {
                const int m0 = row0A + wm * 64 + i * 16 + (lane >> 4) * 4;
#pragma unroll
                for (int r = 0; r < 4; ++r) {
                    float v = acc[i][j][r] + bj;
                    if (EPI == 2) v = fmaxf(v, 0.f);
                    if (EPI == 3) {
                        o1[(size_t)(m0 + r) * pitchO + n] = v;
                    } else {
                        const unsigned short h = f2b(v);
                        const unsigned short l = f2b(v - b2f(h));
                        okh[(size_t)(m0 + r) * pitchO + n] = h;
                        okl[(size_t)(m0 + r) * pitchO + n] = l;
                    }
                }
            }
        }
    }
}

// ---------------- W transpose + split: W[K][N] fp32 -> Th/Tl [N][K] bf16 ----
__global__ __launch_bounds__(256) void wtsplit_kernel(
    const float* __restrict__ W, unsigned short* __restrict__ th,
    unsigned short* __restrict__ tl, int K, int N)
{
    __shared__ float t[32][33];
    const int k0 = blockIdx.y * 32, n0 = blockIdx.x * 32;
    const int r = threadIdx.x >> 5, c = threadIdx.x & 31;
#pragma unroll
    for (int p = 0; p < 4; ++p)
        t[r + p * 8][c] = W[(size_t)(k0 + r + p * 8) * N + n0 + c];
    __syncthreads();
#pragma unroll
    for (int p = 0; p < 4; ++p) {
        const int rn = r + p * 8;
        const float v = t[c][rn];
        const unsigned short h = f2b(v);
        const size_t o = (size_t)(n0 + rn) * K + k0 + c;
        th[o] = h;
        tl[o] = f2b(v - b2f(h));
    }
}

// ---------------- vectorized split: fp32 -> hi/lo bf16 (4 elems/thread) ----
__global__ __launch_bounds__(256) void split4_kernel(
    const float* __restrict__ in, unsigned short* __restrict__ oh,
    unsigned short* __restrict__ ol, int n4)
{
    const int i = blockIdx.x * 256 + threadIdx.x;
    if (i < n4) {
        const f4 v = ((const f4*)in)[i];
        ushort4 hv, lv;
        hv.x = f2b(v.x); lv.x = f2b(v.x - b2f(hv.x));
        hv.y = f2b(v.y); lv.y = f2b(v.y - b2f(hv.y));
        hv.z = f2b(v.z); lv.z = f2b(v.z - b2f(hv.z));
        hv.w = f2b(v.w); lv.w = f2b(v.w - b2f(hv.w));
        ((ushort4*)oh)[i] = hv;
        ((ushort4*)ol)[i] = lv;
    }
}

// ---------------- top-k -> bf16 gating matrix (high-occupancy) ----
__device__ __forceinline__ void ins4(float s, int m,
    float& v0, float& v1, float& v2, float& v3,
    int& i0, int& i1, int& i2, int& i3)
{
    if (s > v3) {
        if (s > v1) {
            if (s > v0) { v3=v2;i3=i2; v2=v1;i2=i1; v1=v0;i1=i0; v0=s;i0=m; }
            else        { v3=v2;i3=i2; v2=v1;i2=i1; v1=s;i1=m; }
        } else {
            if (s > v2) { v3=v2;i3=i2; v2=s;i2=m; }
            else        { v3=s;i3=m; }
        }
    }
}

__global__ __launch_bounds__(256) void topk_gating_kernel(
    const float* __restrict__ scores,        // [8,256,32768]
    unsigned short* __restrict__ gating,     // [8*256][32768] bf16, pre-zeroed
    int* __restrict__ counts)                // [8,256] (pre-zeroed)
{
    __shared__ int cnt[MS];
    const int tid = threadIdx.x;
    const int h = blockIdx.y;
    const int n = blockIdx.x * 256 + tid;

    cnt[tid] = 0;
    __syncthreads();

    float v0 = -FLT_MAX, v1 = -FLT_MAX, v2 = -FLT_MAX, v3 = -FLT_MAX;
    int i0 = 0, i1 = 0, i2 = 0, i3 = 0;
    const float* sp = scores + (size_t)(h * MS) * TOK + n;
    for (int m0 = 0; m0 < MS; m0 += 8) {
        float s[8];
#pragma unroll
        for (int j = 0; j < 8; ++j) s[j] = sp[(size_t)(m0 + j) * TOK];
#pragma unroll
        for (int j = 0; j < 8; ++j) ins4(s[j], m0 + j, v0, v1, v2, v3, i0, i1, i2, i3);
    }

    const size_t gb = (size_t)(h * MS) * TOK + n;
    gating[gb + (size_t)i0 * TOK] = 0x3F80;   // bf16 1.0
    gating[gb + (size_t)i1 * TOK] = 0x3F80;
    gating[gb + (size_t)i2 * TOK] = 0x3F80;
    gating[gb + (size_t)i3 * TOK] = 0x3F80;

    atomicAdd(&cnt[i0], 1); atomicAdd(&cnt[i1], 1);
    atomicAdd(&cnt[i2], 1); atomicAdd(&cnt[i3], 1);
    __syncthreads();
    atomicAdd(&counts[h * MS + tid], cnt[tid]);
}

// ---------------- kv transpose: kvh/kvl [TOK][CO] -> kvTh/kvTl [CO][TOK] ----
__global__ __launch_bounds__(256) void kvt_kernel(
    const unsigned short* __restrict__ sh, const unsigned short* __restrict__ sl,
    unsigned short* __restrict__ dh, unsigned short* __restrict__ dl)
{
    __shared__ unsigned short t[64][68];   // pad 4 shorts
    const int n0 = blockIdx.x * 64;
    const int c0 = blockIdx.y * 64;
    const int r = threadIdx.x >> 4;          // 0..15
    const int c4 = (threadIdx.x & 15) * 4;   // 0..60

#pragma unroll
    for (int pass = 0; pass < 2; ++pass) {
        const unsigned short* s = pass ? sl : sh;
        unsigned short* d = pass ? dl : dh;
        if (pass) __syncthreads();
#pragma unroll
        for (int p = 0; p < 4; ++p)
            *(ushort4*)&t[p * 16 + r][c4] =
                *(const ushort4*)&s[(size_t)(n0 + p * 16 + r) * CO + c0 + c4];
        __syncthreads();
#pragma unroll
        for (int p = 0; p < 4; ++p) {
            const int cc = p * 16 + r;
            ushort4 v;
            v.x = t[c4 + 0][cc]; v.y = t[c4 + 1][cc];
            v.z = t[c4 + 2][cc]; v.w = t[c4 + 3][cc];
            *(ushort4*)&d[(size_t)(c0 + cc) * TOK + n0 + c4] = v;
        }
    }
}

// ---------------- attended = gating @ kvT^T via MFMA, split-K (BK=32) ----
__global__ __launch_bounds__(256) void gather_gemm(
    const unsigned short* __restrict__ G,
    const unsigned short* __restrict__ BTh, const unsigned short* __restrict__ BTl,
    float* __restrict__ part)               // [SKC][8][256][128]
{
    __shared__ unsigned short smem[3 * 4096];   // Ag | Bh | Bl, each [128][32]
    const int tid = threadIdx.x, lane = tid & 63, wv = tid >> 6;
    const int wm = wv >> 1, wn = wv & 1;
    const int kc = blockIdx.x;
    const int mb = blockIdx.y;
    const int h  = blockIdx.z;
    const int row0A = h * MS + mb * 128;
    const int row0B = h * HDIM;
    const int k0 = kc * (TOK / SKC);

    f32x4 acc[4][4];
#pragma unroll
    for (int i = 0; i < 4; ++i)
#pragma unroll
        for (int j = 0; j < 4; ++j) acc[i][j] = (f32x4){0.f, 0.f, 0.f, 0.f};

    for (int ks = 0; ks < (TOK / SKC) / 32; ++ks) {
        const int acol = k0 + ks * 32;
#pragma unroll
        for (int j = 0; j < 2; ++j) {
            const int c    = wv * 2 + j;
            const int grow = c * 16 + (lane >> 2);
            const int osrc = (lane & 3) ^ (grow & 3);
            gload16(G + (size_t)(row0A + grow) * TOK + acol + osrc * 8,
                    &smem[c * 512]);
        }
#pragma unroll
        for (int t = 1; t < 3; ++t) {
            const unsigned short* src = (t == 1) ? BTh : BTl;
#pragma unroll
            for (int j = 0; j < 2; ++j) {
                const int c    = wv * 2 + j;
                const int grow = c * 16 + (lane >> 2);
                const int osrc = (lane & 3) ^ (grow & 3);
                gload16(src + (size_t)(row0B + grow) * TOK + acol + osrc * 8,
                        &smem[t * 4096 + c * 512]);
            }
        }
        __syncthreads();

        bf16x8 ag[4], bh[4], bl[4];
#pragma unroll
        for (int f = 0; f < 4; ++f) {
            const int ra = wm * 64 + f * 16 + (lane & 15);
            const int rb = wn * 64 + f * 16 + (lane & 15);
            const int ka = (lane >> 4) ^ (ra & 3);
            const int kb = (lane >> 4) ^ (rb & 3);
            ag[f] = *(const bf16x8*)&smem[          ra * 32 + ka * 8];
            bh[f] = *(const bf16x8*)&smem[1 * 4096 + rb * 32 + kb * 8];
            bl[f] = *(const bf16x8*)&smem[2 * 4096 + rb * 32 + kb * 8];
        }
#pragma unroll
        for (int i = 0; i < 4; ++i)
#pragma unroll
            for (int j = 0; j < 4; ++j) {
                acc[i][j] = __builtin_amdgcn_mfma_f32_16x16x32_bf16(ag[i], bh[j], acc[i][j], 0, 0, 0);
                acc[i][j] = __builtin_amdgcn_mfma_f32_16x16x32_bf16(ag[i], bl[j], acc[i][j], 0, 0, 0);
            }
        __syncthreads();
    }

    const size_t base = ((size_t)kc * NH + h) * MS;
#pragma unroll
    for (int i = 0; i < 4; ++i) {
        const int ml0 = mb * 128 + wm * 64 + i * 16 + (lane >> 4) * 4;
#pragma unroll
        for (int r = 0; r < 4; ++r) {
            const size_t rowo = (base + ml0 + r) * HDIM;
#pragma unroll
            for (int j = 0; j < 4; ++j) {
                const int d = wn * 64 + j * 16 + (lane & 15);
                part[rowo + d] = acc[i][j][r];
            }
        }
    }
}

// ---------------- reduce split-K partials -> attended ----
__global__ __launch_bounds__(256) void red_kernel(
    const float* __restrict__ part, float* __restrict__ att)
{
    const int o = blockIdx.x * 256 + threadIdx.x;
    const int stride = NH * MS * HDIM;
    float s = 0.f;
#pragma unroll
    for (int k = 0; k < SKC; ++k) s += part[(size_t)k * stride + o];
    att[o] = s;
}

// ---------------- block reduce helper (sum, sumsq) ----
__device__ __forceinline__ void block_reduce2(float& s, float& sq) {
    for (int o = 32; o > 0; o >>= 1) {
        s  += __shfl_down(s, o);
        sq += __shfl_down(sq, o);
    }
    __shared__ float ls[4], lsq[4];
    const int w = threadIdx.x >> 6, lane = threadIdx.x & 63;
    if (lane == 0) { ls[w] = s; lsq[w] = sq; }
    __syncthreads();
    s  = ls[0] + ls[1] + ls[2] + ls[3];
    sq = lsq[0] + lsq[1] + lsq[2] + lsq[3];
}

// ---------------- LN over concat([mem, context]) rows of 2048 ----
__global__ __launch_bounds__(256) void ln1_kernel(
    const float* __restrict__ mem, const float* __restrict__ attended,
    const float* __restrict__ g, const float* __restrict__ bb,
    float* __restrict__ h1)
{
    const int m = blockIdx.x, tid = threadIdx.x;
    float x[8];
#pragma unroll
    for (int i = 0; i < 8; ++i) {
        const int col = i * 256 + tid;
        if (col < CO) {
            x[i] = mem[(size_t)m * CO + col];
        } else {
            const int cc = col - CO;
            x[i] = attended[(size_t)((cc >> 7) * MS + m) * HDIM + (cc & 127)];
        }
    }
    float s = 0.f, sq = 0.f;
#pragma unroll
    for (int i = 0; i < 8; ++i) { s += x[i]; sq += x[i] * x[i]; }
    block_reduce2(s, sq);
    const float mu = s * (1.0f / IN2);
    const float var = sq * (1.0f / IN2) - mu * mu;
    const float rs = rsqrtf(var + 1e-5f);
#pragma unroll
    for (int i = 0; i < 8; ++i) {
        const int col = i * 256 + tid;
        h1[(size_t)m * IN2 + col] = (x[i] - mu) * rs * g[col] + bb[col];
    }
}

// ---------------- final LN over rows of 1024 -> dyn output ----
__global__ __launch_bounds__(256) void ln2_kernel(
    const float* __restrict__ in, const float* __restrict__ g,
    const float* __restrict__ bb, float* __restrict__ out)
{
    const int m = blockIdx.x, tid = threadIdx.x;
    float x[4];
#pragma unroll
    for (int i = 0; i < 4; ++i) x[i] = in[(size_t)m * CO + i * 256 + tid];
    float s = 0.f, sq = 0.f;
#pragma unroll
    for (int i = 0; i < 4; ++i) { s += x[i]; sq += x[i] * x[i]; }
    block_reduce2(s, sq);
    const float mu = s * (1.0f / CO);
    const float var = sq * (1.0f / CO) - mu * mu;
    const float rs = rsqrtf(var + 1e-5f);
#pragma unroll
    for (int i = 0; i < 4; ++i) {
        const int col = i * 256 + tid;
        out[(size_t)m * CO + col] = (x[i] - mu) * rs * g[col] + bb[col];
    }
}

// ---------------- load_fraction[m] = sum_h counts[h][m] / 8 ----
__global__ __launch_bounds__(256) void lf_kernel(
    const int* __restrict__ counts, float* __restrict__ out)
{
    const int m = threadIdx.x;
    float s = 0.f;
#pragma unroll
    for (int h = 0; h < NH; ++h) s += (float)counts[h * MS + m];
    out[m] = s * 0.125f;
}

extern "C" void kernel_launch(void* const* d_in, const int* in_sizes, int n_in,
                              void* d_out, int out_size, void* d_ws, size_t ws_size,
                              hipStream_t stream)
{
    const float* bqry = (const float*)d_in[0];   // [32768][2048]
    const float* memb = (const float*)d_in[1];   // [256][1024]
    const float* Wq   = (const float*)d_in[2];   // [2048][1024]
    const float* bq   = (const float*)d_in[3];
    const float* Ws1  = (const float*)d_in[4];   // [1024][4096]
    const float* bs1  = (const float*)d_in[5];
    const float* Ws2  = (const float*)d_in[6];   // [4096][1024]
    const float* bs2  = (const float*)d_in[7];
    const float* mbia = (const float*)d_in[8];   // [8,256,1]
    const float* ln1g = (const float*)d_in[9];
    const float* ln1b = (const float*)d_in[10];
    const float* Wu1  = (const float*)d_in[11];  // [2048][2048]
    const float* bu1  = (const float*)d_in[12];
    const float* Wu2  = (const float*)d_in[13];  // [2048][1024]
    const float* bu2  = (const float*)d_in[14];
    const float* lnog = (const float*)d_in[15];
    const float* lnob = (const float*)d_in[16];

    float* out = (float*)d_out;
    float* dyn_out = out;                                   // 256*1024
    float* sc1 = out + (size_t)MS * CO;                     // scores_div
    float* sc2 = sc1 + (size_t)NH * MS * TOK;               // gate_logits
    float* lf  = sc2 + (size_t)NH * MS * TOK;               // [256]

    char* wsp = (char*)d_ws;
    auto alloc = [&](size_t bytes) {
        char* p = wsp;
        wsp += (bytes + 255) & ~(size_t)255;
        return p;
    };
    // Aliased region: bqh/bql (268 MB) die after the kv GEMM; kvT + gat are
    // laid exactly over them (written strictly afterwards).
    char* region = alloc(2 * (size_t)TOK * DM * 2);                    // 268 MB
    unsigned short* bqh  = (unsigned short*)region;
    unsigned short* bql  = bqh + (size_t)TOK * DM;
    unsigned short* kvTh = (unsigned short*)region;                    // alias
    unsigned short* kvTl = kvTh + (size_t)CO * TOK;
    unsigned short* gat  = kvTl + (size_t)CO * TOK;                    // 134 MB

    unsigned short* kvh  = (unsigned short*)alloc((size_t)TOK * CO * 2);
    unsigned short* kvl  = (unsigned short*)alloc((size_t)TOK * CO * 2);
    float* part = (float*)alloc((size_t)SKC * NH * MS * HDIM * 4);     // 34 MB
    unsigned short* WqTh  = (unsigned short*)alloc((size_t)CO * DM * 2);
    unsigned short* WqTl  = (unsigned short*)alloc((size_t)CO * DM * 2);
    unsigned short* Ws1Th = (unsigned short*)alloc((size_t)ITR * CO * 2);
    unsigned short* Ws1Tl = (unsigned short*)alloc((size_t)ITR * CO * 2);
    unsigned short* Ws2Th = (unsigned short*)alloc((size_t)CO * ITR * 2);
    unsigned short* Ws2Tl = (unsigned short*)alloc((size_t)CO * ITR * 2);
    unsigned short* Wu1Th = (unsigned short*)alloc((size_t)IN2 * IN2 * 2);
    unsigned short* Wu1Tl = (unsigned short*)alloc((size_t)IN2 * IN2 * 2);
    unsigned short* Wu2Th = (unsigned short*)alloc((size_t)CO * IN2 * 2);
    unsigned short* Wu2Tl = (unsigned short*)alloc((size_t)CO * IN2 * 2);
    unsigned short* mh  = (unsigned short*)alloc((size_t)MS * CO * 2);
    unsigned short* ml  = (unsigned short*)alloc((size_t)MS * CO * 2);
    unsigned short* hqh = (unsigned short*)alloc((size_t)MS * ITR * 2);
    unsigned short* hql = (unsigned short*)alloc((size_t)MS * ITR * 2);
    unsigned short* qsh = (unsigned short*)alloc((size_t)MS * CO * 2);
    unsigned short* qsl = (unsigned short*)alloc((size_t)MS * CO * 2);
    unsigned short* h1h = (unsigned short*)alloc((size_t)MS * IN2 * 2);
    unsigned short* h1l = (unsigned short*)alloc((size_t)MS * IN2 * 2);
    unsigned short* huh = (unsigned short*)alloc((size_t)MS * IN2 * 2);
    unsigned short* hul = (unsigned short*)alloc((size_t)MS * IN2 * 2);
    float* h1  = (float*)alloc((size_t)MS * IN2 * 4);
    float* h2  = (float*)alloc((size_t)MS * CO * 4);
    float* att = (float*)alloc((size_t)NH * MS * HDIM * 4);
    int*  counts = (int*)alloc((size_t)NH * MS * 4);

    const dim3 blk(256);

    // --- input splits & weight transposes ---
    split4_kernel<<<dim3(TOK * DM / 4 / 256), blk, 0, stream>>>(bqry, bqh, bql, TOK * DM / 4);
    split4_kernel<<<dim3(MS * CO / 4 / 256), blk, 0, stream>>>(memb, mh, ml, MS * CO / 4);
    wtsplit_kernel<<<dim3(CO / 32, DM / 32), blk, 0, stream>>>(Wq, WqTh, WqTl, DM, CO);
    wtsplit_kernel<<<dim3(ITR / 32, CO / 32), blk, 0, stream>>>(Ws1, Ws1Th, Ws1Tl, CO, ITR);
    wtsplit_kernel<<<dim3(CO / 32, ITR / 32), blk, 0, stream>>>(Ws2, Ws2Th, Ws2Tl, ITR, CO);
    wtsplit_kernel<<<dim3(IN2 / 32, IN2 / 32), blk, 0, stream>>>(Wu1, Wu1Th, Wu1Tl, IN2, IN2);
    wtsplit_kernel<<<dim3(CO / 32, IN2 / 32), blk, 0, stream>>>(Wu2, Wu2Th, Wu2Tl, IN2, CO);

    // --- q_slots MLP: relu(mem@Ws1+bs1)@Ws2+bs2 -> qsh/qsl ---
    mfma64<2, false><<<dim3(ITR / 128, MS / 128, 1), blk, 0, stream>>>(
        mh, ml, Ws1Th, Ws1Tl, CO, CO, ITR, CO / 64, 0, bs1,
        nullptr, nullptr, hqh, hql);
    mfma64<0, false><<<dim3(CO / 128, MS / 128, 1), blk, 0, stream>>>(
        hqh, hql, Ws2Th, Ws2Tl, ITR, ITR, CO, ITR / 64, 0, bs2,
        nullptr, nullptr, qsh, qsl);

    // --- kv = flat@Wq+bq (XCD-grouped 1-D grid: 8 x-blocks/strip -> 1 XCD) ---
    mfma64<0, true><<<dim3((CO / 128) * (TOK / 128), 1, 1), blk, 0, stream>>>(
        bqh, bql, WqTh, WqTl, DM, DM, CO, DM / 64, 0, bq,
        nullptr, nullptr, kvh, kvl);

    // --- kv transpose (overwrites dead bqh region) ---
    kvt_kernel<<<dim3(TOK / 64, CO / 64), blk, 0, stream>>>(kvh, kvl, kvTh, kvTl);

    // --- zero gating + counts/att (gat overwrites dead bql region) ---
    hipMemsetAsync(gat, 0, (size_t)NH * MS * TOK * 2, stream);
    hipMemsetAsync(counts, 0, (size_t)NH * MS * 4, stream);

    // --- scores (dual fp32 write) ---
    mfma64<1, false><<<dim3(TOK / 128, MS / 128, NH), blk, 0, stream>>>(
        qsh, qsl, kvh, kvl, CO, CO, TOK, HDIM / 64, HDIM, mbia,
        sc1, sc2, nullptr, nullptr);

    // --- top-k -> gating matrix + counts ---
    topk_gating_kernel<<<dim3(TOK / 256, NH), blk, 0, stream>>>(sc2, gat, counts);

    // --- attended = gating @ kv (split-K MFMA) ---
    gather_gemm<<<dim3(SKC, 2, NH), blk, 0, stream>>>(gat, kvTh, kvTl, part);
    red_kernel<<<dim3(NH * MS * HDIM / 256), blk, 0, stream>>>(part, att);

    // --- update MLP ---
    ln1_kernel<<<dim3(MS), blk, 0, stream>>>(memb, att, ln1g, ln1b, h1);
    split4_kernel<<<dim3(MS * IN2 / 4 / 256), blk, 0, stream>>>(h1, h1h, h1l, MS * IN2 / 4);
    mfma64<2, false><<<dim3(IN2 / 128, MS / 128, 1), blk, 0, stream>>>(
        h1h, h1l, Wu1Th, Wu1Tl, IN2, IN2, IN2, IN2 / 64, 0, bu1,
        nullptr, nullptr, huh, hul);
    mfma64<3, false><<<dim3(CO / 128, MS / 128, 1), blk, 0, stream>>>(
        huh, hul, Wu2Th, Wu2Tl, IN2, IN2, CO, IN2 / 64, 0, bu2,
        h2, nullptr, nullptr, nullptr);
    ln2_kernel<<<dim3(MS), blk, 0, stream>>>(h2, lnog, lnob, dyn_out);

    lf_kernel<<<1, blk, 0, stream>>>(counts, lf);
}

// Round 9
// 1849.799 us; speedup vs baseline: 1.7597x; 1.1181x over previous
//
#include <hip/hip_runtime.h>
#include <float.h>

#define TOK   32768   // B*S
#define DM    2048    // D_MODEL
#define CO    1024    // CORE
#define MS    256     // M slots
#define NH    8       // heads
#define HDIM  128     // head dim
#define IN2   2048    // 2*CORE
#define ITR   4096    // CORE*FACTOR
#define SKC   32      // split-K chunks for gather_gemm

typedef float4 f4;
typedef __attribute__((ext_vector_type(8))) short bf16x8;
typedef __attribute__((ext_vector_type(4))) float f32x4;

__device__ __forceinline__ unsigned short f2b(float x) {   // fp32 -> bf16 RNE
    unsigned int u = __float_as_uint(x);
    u += 0x7fff + ((u >> 16) & 1);
    return (unsigned short)(u >> 16);
}
__device__ __forceinline__ float b2f(unsigned short s) {
    return __uint_as_float(((unsigned int)s) << 16);
}

__device__ __forceinline__ void gload16(const void* g, void* l) {
    __builtin_amdgcn_global_load_lds(
        (const __attribute__((address_space(1))) unsigned int*)g,
        (__attribute__((address_space(3))) unsigned int*)l, 16, 0, 0);
}

// =====================================================================
// Split-bf16 MFMA GEMM, 128x128 tile, 4 waves, BK=64, 2 barriers/K-step.
// C = A @ B^T (NT row-major), A=Ah+Al, B=Bh+Bl, acc += AhBh + AhBl + AlBh.
// LDS [128][64] bf16 rows (=32 banks), 8-slot XOR chunk swizzle, source
// pre-permuted for linear gload_lds (validated: 0 bank conflicts, r8).
// EPI: 0 = +bias, split-bf16 out
//      1 = scores: *scale + 5*rowbias, dual fp32 out
//      4 = raw fp32 partial out at [z][M][N] (split-K)
// SWZ: 0 = plain 3-D grid (z: split-K slice via coffMul)
//      1 = kv XCD-grouping (1-D grid 2048, A-strip per XCD)
//      2 = scores XCD-pairing (1-D grid 4096; the two m-tiles sharing a
//          kv token-tile are consecutive on the same XCD; z folded in)
// =====================================================================
template<int EPI, int SWZ>
__global__ __launch_bounds__(256) void mfma64(
    const unsigned short* __restrict__ Abh, const unsigned short* __restrict__ Abl,
    const unsigned short* __restrict__ Bh,  const unsigned short* __restrict__ Bl,
    int pitchA, int pitchB, int pitchO, int ksteps, int coffMul,
    const float* __restrict__ bias,
    float* __restrict__ o1, float* __restrict__ o2,
    unsigned short* __restrict__ okh, unsigned short* __restrict__ okl)
{
    __shared__ unsigned short smem[4 * 8192];   // Ah|Al|Bh|Bl, each [128][64]

    const int tid  = threadIdx.x;
    const int lane = tid & 63;
    const int wv   = tid >> 6;
    const int wm   = wv >> 1, wn = wv & 1;

    int bx, by, hz;
    if (SWZ == 1) {                      // kv: nbx=8 (CO/128), nby=256
        const int b = blockIdx.x;
        const int xcd = b & 7;
        const int t = b >> 3;
        bx = t & 7;
        by = (t >> 3) * 8 + xcd;
        hz = 0;
    } else if (SWZ == 2) {               // scores: tt 0..255, mb 0..1, h 0..7
        const int b = blockIdx.x;        // 0..4095
        const int xcd = b & 7;
        const int j = b >> 3;
        by = j & 1;                      // m tile
        const int pair = (j >> 1) * 8 + xcd;   // 0..2047 (bijective)
        bx = pair & 255;                 // kv token tile
        hz = pair >> 8;                  // head
    } else {
        bx = blockIdx.x; by = blockIdx.y; hz = blockIdx.z;
    }
    const int row0A = by * 128;
    const int row0B = bx * 128;
    const int coff  = coffMul * hz;

    f32x4 acc[4][4];
#pragma unroll
    for (int i = 0; i < 4; ++i)
#pragma unroll
        for (int j = 0; j < 4; ++j) acc[i][j] = (f32x4){0.f, 0.f, 0.f, 0.f};

    for (int ks = 0; ks < ksteps; ++ks) {
        const int acol = coff + ks * 64;
#pragma unroll
        for (int j = 0; j < 4; ++j) {
            const int c    = wv * 4 + j;            // chunk: 8 rows x 64 cols
            const int grow = c * 8 + (lane >> 3);
            const int osrc = (lane & 7) ^ (grow & 7);
            const size_t ga = (size_t)(row0A + grow) * pitchA + acol + osrc * 8;
            const size_t gb = (size_t)(row0B + grow) * pitchB + acol + osrc * 8;
            gload16(Abh + ga, &smem[0 * 8192 + c * 512]);
            gload16(Abl + ga, &smem[1 * 8192 + c * 512]);
            gload16(Bh  + gb, &smem[2 * 8192 + c * 512]);
            gload16(Bl  + gb, &smem[3 * 8192 + c * 512]);
        }
        __syncthreads();   // drains vmcnt (gload_lds writes landed)

#pragma unroll
        for (int s = 0; s < 2; ++s) {          // two 32-k sub-steps
            bf16x8 ah[4], al[4], bh[4], bl[4];
#pragma unroll
            for (int f = 0; f < 4; ++f) {
                const int ra = wm * 64 + f * 16 + (lane & 15);
                const int rb = wn * 64 + f * 16 + (lane & 15);
                const int ka = s * 4 + (lane >> 4);
                const int oa = ka ^ (ra & 7);
                const int ob = ka ^ (rb & 7);
                ah[f] = *(const bf16x8*)&smem[0 * 8192 + ra * 64 + oa * 8];
                al[f] = *(const bf16x8*)&smem[1 * 8192 + ra * 64 + oa * 8];
                bh[f] = *(const bf16x8*)&smem[2 * 8192 + rb * 64 + ob * 8];
                bl[f] = *(const bf16x8*)&smem[3 * 8192 + rb * 64 + ob * 8];
            }
#pragma unroll
            for (int i = 0; i < 4; ++i)
#pragma unroll
                for (int j = 0; j < 4; ++j) {
                    acc[i][j] = __builtin_amdgcn_mfma_f32_16x16x32_bf16(al[i], bh[j], acc[i][j], 0, 0, 0);
                    acc[i][j] = __builtin_amdgcn_mfma_f32_16x16x32_bf16(ah[i], bl[j], acc[i][j], 0, 0, 0);
                    acc[i][j] = __builtin_amdgcn_mfma_f32_16x16x32_bf16(ah[i], bh[j], acc[i][j], 0, 0, 0);
                }
        }
        __syncthreads();   // reads done before next overwrite
    }

    // epilogue. C/D frag: col = lane&15, row = (lane>>4)*4 + reg
    if (EPI == 1) {
        const float scale = 0.08838834764831845f; // 1/sqrt(128)
#pragma unroll
        for (int i = 0; i < 4; ++i) {
            const int m0 = row0A + wm * 64 + i * 16 + (lane >> 4) * 4;
#pragma unroll
            for (int r = 0; r < 4; ++r) {
                const float b5 = 5.0f * bias[hz * MS + m0 + r];
                const size_t rowo = (size_t)(hz * MS + m0 + r) * TOK;
#pragma unroll
                for (int j = 0; j < 4; ++j) {
                    const int n = row0B + wn * 64 + j * 16 + (lane & 15);
                    const float v = acc[i][j][r] * scale + b5;
                    o1[rowo + n] = v;
                    o2[rowo + n] = v;
                }
            }
        }
    } else if (EPI == 4) {
#pragma unroll
        for (int j = 0; j < 4; ++j) {
            const int n = row0B + wn * 64 + j * 16 + (lane & 15);
#pragma unroll
            for (int i = 0; i < 4; ++i) {
                const int m0 = row0A + wm * 64 + i * 16 + (lane >> 4) * 4;
#pragma unroll
                for (int r = 0; r < 4; ++r)
                    o1[((size_t)hz * MS + m0 + r) * pitchO + n] = acc[i][j][r];
            }
        }
    } else {   // EPI == 0
#pragma unroll
        for (int j = 0; j < 4; ++j) {
            const int n  = row0B + wn * 64 + j * 16 + (lane & 15);
            const float bj = bias[n];
#pragma unroll
            for (int i = 0; i < 4; ++i) {
                const int m0 = row0A + wm * 64 + i * 16 + (lane >> 4) * 4;
#pragma unroll
                for (int r = 0; r < 4; ++r) {
                    const float v = acc[i][j][r] + bj;
                    const unsigned short h = f2b(v);
                    const unsigned short l = f2b(v - b2f(h));
                    okh[(size_t)(m0 + r) * pitchO + n] = h;
                    okl[(size_t)(m0 + r) * pitchO + n] = l;
                }
            }
        }
    }
}

// ---------------- split-K finish: sum partials + bias (+relu) -> out ----
// OUT 0: split bf16 (oh/ol); OUT 1: fp32 (of)
template<bool RELU, int OUT>
__global__ __launch_bounds__(256) void finish_kernel(
    const float* __restrict__ part, const float* __restrict__ bias,
    int N, int SK,
    unsigned short* __restrict__ oh, unsigned short* __restrict__ ol,
    float* __restrict__ of)
{
    const int i = blockIdx.x * 256 + threadIdx.x;   // f4 index over M*N/4
    const int MN4 = MS * N / 4;
    f4 s = ((const f4*)part)[i];
    for (int k = 1; k < SK; ++k) {
        const f4 p = ((const f4*)part)[(size_t)k * MN4 + i];
        s.x += p.x; s.y += p.y; s.z += p.z; s.w += p.w;
    }
    const int n0 = (i * 4) % N;
    const f4 b = *(const f4*)&bias[n0];
    s.x += b.x; s.y += b.y; s.z += b.z; s.w += b.w;
    if (RELU) {
        s.x = fmaxf(s.x, 0.f); s.y = fmaxf(s.y, 0.f);
        s.z = fmaxf(s.z, 0.f); s.w = fmaxf(s.w, 0.f);
    }
    if (OUT == 1) {
        ((f4*)of)[i] = s;
    } else {
        ushort4 hv, lv;
        hv.x = f2b(s.x); lv.x = f2b(s.x - b2f(hv.x));
        hv.y = f2b(s.y); lv.y = f2b(s.y - b2f(hv.y));
        hv.z = f2b(s.z); lv.z = f2b(s.z - b2f(hv.z));
        hv.w = f2b(s.w); lv.w = f2b(s.w - b2f(hv.w));
        ((ushort4*)oh)[i] = hv;
        ((ushort4*)ol)[i] = lv;
    }
}

// ---------------- W transpose + split: W[K][N] fp32 -> Th/Tl [N][K] bf16 ----
__global__ __launch_bounds__(256) void wtsplit_kernel(
    const float* __restrict__ W, unsigned short* __restrict__ th,
    unsigned short* __restrict__ tl, int K, int N)
{
    __shared__ float t[32][33];
    const int k0 = blockIdx.y * 32, n0 = blockIdx.x * 32;
    const int r = threadIdx.x >> 5, c = threadIdx.x & 31;
#pragma unroll
    for (int p = 0; p < 4; ++p)
        t[r + p * 8][c] = W[(size_t)(k0 + r + p * 8) * N + n0 + c];
    __syncthreads();
#pragma unroll
    for (int p = 0; p < 4; ++p) {
        const int rn = r + p * 8;
        const float v = t[c][rn];
        const unsigned short h = f2b(v);
        const size_t o = (size_t)(n0 + rn) * K + k0 + c;
        th[o] = h;
        tl[o] = f2b(v - b2f(h));
    }
}

// ---------------- vectorized split: fp32 -> hi/lo bf16 (4 elems/thread) ----
__global__ __launch_bounds__(256) void split4_kernel(
    const float* __restrict__ in, unsigned short* __restrict__ oh,
    unsigned short* __restrict__ ol, int n4)
{
    const int i = blockIdx.x * 256 + threadIdx.x;
    if (i < n4) {
        const f4 v = ((const f4*)in)[i];
        ushort4 hv, lv;
        hv.x = f2b(v.x); lv.x = f2b(v.x - b2f(hv.x));
        hv.y = f2b(v.y); lv.y = f2b(v.y - b2f(hv.y));
        hv.z = f2b(v.z); lv.z = f2b(v.z - b2f(hv.z));
        hv.w = f2b(v.w); lv.w = f2b(v.w - b2f(hv.w));
        ((ushort4*)oh)[i] = hv;
        ((ushort4*)ol)[i] = lv;
    }
}

// ---------------- top-k -> bf16 gating matrix (high-occupancy) ----
__device__ __forceinline__ void ins4(float s, int m,
    float& v0, float& v1, float& v2, float& v3,
    int& i0, int& i1, int& i2, int& i3)
{
    if (s > v3) {
        if (s > v1) {
            if (s > v0) { v3=v2;i3=i2; v2=v1;i2=i1; v1=v0;i1=i0; v0=s;i0=m; }
            else        { v3=v2;i3=i2; v2=v1;i2=i1; v1=s;i1=m; }
        } else {
            if (s > v2) { v3=v2;i3=i2; v2=s;i2=m; }
            else        { v3=s;i3=m; }
        }
    }
}

__global__ __launch_bounds__(256) void topk_gating_kernel(
    const float* __restrict__ scores,        // [8,256,32768]
    unsigned short* __restrict__ gating,     // [8*256][32768] bf16, pre-zeroed
    int* __restrict__ counts)                // [8,256] (pre-zeroed)
{
    __shared__ int cnt[MS];
    const int tid = threadIdx.x;
    const int h = blockIdx.y;
    const int n = blockIdx.x * 256 + tid;

    cnt[tid] = 0;
    __syncthreads();

    float v0 = -FLT_MAX, v1 = -FLT_MAX, v2 = -FLT_MAX, v3 = -FLT_MAX;
    int i0 = 0, i1 = 0, i2 = 0, i3 = 0;
    const float* sp = scores + (size_t)(h * MS) * TOK + n;
    for (int m0 = 0; m0 < MS; m0 += 8) {
        float s[8];
#pragma unroll
        for (int j = 0; j < 8; ++j) s[j] = sp[(size_t)(m0 + j) * TOK];
#pragma unroll
        for (int j = 0; j < 8; ++j) ins4(s[j], m0 + j, v0, v1, v2, v3, i0, i1, i2, i3);
    }

    const size_t gb = (size_t)(h * MS) * TOK + n;
    gating[gb + (size_t)i0 * TOK] = 0x3F80;   // bf16 1.0
    gating[gb + (size_t)i1 * TOK] = 0x3F80;
    gating[gb + (size_t)i2 * TOK] = 0x3F80;
    gating[gb + (size_t)i3 * TOK] = 0x3F80;

    atomicAdd(&cnt[i0], 1); atomicAdd(&cnt[i1], 1);
    atomicAdd(&cnt[i2], 1); atomicAdd(&cnt[i3], 1);
    __syncthreads();
    atomicAdd(&counts[h * MS + tid], cnt[tid]);
}

// ---------------- kv transpose: kvh/kvl [TOK][CO] -> kvTh/kvTl [CO][TOK] ----
__global__ __launch_bounds__(256) void kvt_kernel(
    const unsigned short* __restrict__ sh, const unsigned short* __restrict__ sl,
    unsigned short* __restrict__ dh, unsigned short* __restrict__ dl)
{
    __shared__ unsigned short t[64][68];   // pad 4 shorts
    const int n0 = blockIdx.x * 64;
    const int c0 = blockIdx.y * 64;
    const int r = threadIdx.x >> 4;          // 0..15
    const int c4 = (threadIdx.x & 15) * 4;   // 0..60

#pragma unroll
    for (int pass = 0; pass < 2; ++pass) {
        const unsigned short* s = pass ? sl : sh;
        unsigned short* d = pass ? dl : dh;
        if (pass) __syncthreads();
#pragma unroll
        for (int p = 0; p < 4; ++p)
            *(ushort4*)&t[p * 16 + r][c4] =
                *(const ushort4*)&s[(size_t)(n0 + p * 16 + r) * CO + c0 + c4];
        __syncthreads();
#pragma unroll
        for (int p = 0; p < 4; ++p) {
            const int cc = p * 16 + r;
            ushort4 v;
            v.x = t[c4 + 0][cc]; v.y = t[c4 + 1][cc];
            v.z = t[c4 + 2][cc]; v.w = t[c4 + 3][cc];
            *(ushort4*)&d[(size_t)(c0 + cc) * TOK + n0 + c4] = v;
        }
    }
}

// ---------------- attended = gating @ kvT^T via MFMA, split-K (BK=32) ----
__global__ __launch_bounds__(256) void gather_gemm(
    const unsigned short* __restrict__ G,
    const unsigned short* __restrict__ BTh, const unsigned short* __restrict__ BTl,
    float* __restrict__ part)               // [SKC][8][256][128]
{
    __shared__ unsigned short smem[3 * 4096];   // Ag | Bh | Bl, each [128][32]
    const int tid = threadIdx.x, lane = tid & 63, wv = tid >> 6;
    const int wm = wv >> 1, wn = wv & 1;
    const int kc = blockIdx.x;
    const int mb = blockIdx.y;
    const int h  = blockIdx.z;
    const int row0A = h * MS + mb * 128;
    const int row0B = h * HDIM;
    const int k0 = kc * (TOK / SKC);

    f32x4 acc[4][4];
#pragma unroll
    for (int i = 0; i < 4; ++i)
#pragma unroll
        for (int j = 0; j < 4; ++j) acc[i][j] = (f32x4){0.f, 0.f, 0.f, 0.f};

    for (int ks = 0; ks < (TOK / SKC) / 32; ++ks) {
        const int acol = k0 + ks * 32;
#pragma unroll
        for (int j = 0; j < 2; ++j) {
            const int c    = wv * 2 + j;
            const int grow = c * 16 + (lane >> 2);
            const int osrc = (lane & 3) ^ (grow & 3);
            gload16(G + (size_t)(row0A + grow) * TOK + acol + osrc * 8,
                    &smem[c * 512]);
        }
#pragma unroll
        for (int t = 1; t < 3; ++t) {
            const unsigned short* src = (t == 1) ? BTh : BTl;
#pragma unroll
            for (int j = 0; j < 2; ++j) {
                const int c    = wv * 2 + j;
                const int grow = c * 16 + (lane >> 2);
                const int osrc = (lane & 3) ^ (grow & 3);
                gload16(src + (size_t)(row0B + grow) * TOK + acol + osrc * 8,
                        &smem[t * 4096 + c * 512]);
            }
        }
        __syncthreads();

        bf16x8 ag[4], bh[4], bl[4];
#pragma unroll
        for (int f = 0; f < 4; ++f) {
            const int ra = wm * 64 + f * 16 + (lane & 15);
            const int rb = wn * 64 + f * 16 + (lane & 15);
            const int ka = (lane >> 4) ^ (ra & 3);
            const int kb = (lane >> 4) ^ (rb & 3);
            ag[f] = *(const bf16x8*)&smem[          ra * 32 + ka * 8];
            bh[f] = *(const bf16x8*)&smem[1 * 4096 + rb * 32 + kb * 8];
            bl[f] = *(const bf16x8*)&smem[2 * 4096 + rb * 32 + kb * 8];
        }
#pragma unroll
        for (int i = 0; i < 4; ++i)
#pragma unroll
            for (int j = 0; j < 4; ++j) {
                acc[i][j] = __builtin_amdgcn_mfma_f32_16x16x32_bf16(ag[i], bh[j], acc[i][j], 0, 0, 0);
                acc[i][j] = __builtin_amdgcn_mfma_f32_16x16x32_bf16(ag[i], bl[j], acc[i][j], 0, 0, 0);
            }
        __syncthreads();
    }

    const size_t base = ((size_t)kc * NH + h) * MS;
#pragma unroll
    for (int i = 0; i < 4; ++i) {
        const int ml0 = mb * 128 + wm * 64 + i * 16 + (lane >> 4) * 4;
#pragma unroll
        for (int r = 0; r < 4; ++r) {
            const size_t rowo = (base + ml0 + r) * HDIM;
#pragma unroll
            for (int j = 0; j < 4; ++j) {
                const int d = wn * 64 + j * 16 + (lane & 15);
                part[rowo + d] = acc[i][j][r];
            }
        }
    }
}

// ---------------- reduce gather split-K partials -> attended ----
__global__ __launch_bounds__(256) void red_kernel(
    const float* __restrict__ part, float* __restrict__ att)
{
    const int o = blockIdx.x * 256 + threadIdx.x;
    const int stride = NH * MS * HDIM;
    float s = 0.f;
#pragma unroll
    for (int k = 0; k < SKC; ++k) s += part[(size_t)k * stride + o];
    att[o] = s;
}

// ---------------- block reduce helper (sum, sumsq) ----
__device__ __forceinline__ void block_reduce2(float& s, float& sq) {
    for (int o = 32; o > 0; o >>= 1) {
        s  += __shfl_down(s, o);
        sq += __shfl_down(sq, o);
    }
    __shared__ float ls[4], lsq[4];
    const int w = threadIdx.x >> 6, lane = threadIdx.x & 63;
    if (lane == 0) { ls[w] = s; lsq[w] = sq; }
    __syncthreads();
    s  = ls[0] + ls[1] + ls[2] + ls[3];
    sq = lsq[0] + lsq[1] + lsq[2] + lsq[3];
}

// ---------------- LN over concat([mem, context]) rows of 2048 ----
__global__ __launch_bounds__(256) void ln1_kernel(
    const float* __restrict__ mem, const float* __restrict__ attended,
    const float* __restrict__ g, const float* __restrict__ bb,
    float* __restrict__ h1)
{
    const int m = blockIdx.x, tid = threadIdx.x;
    float x[8];
#pragma unroll
    for (int i = 0; i < 8; ++i) {
        const int col = i * 256 + tid;
        if (col < CO) {
            x[i] = mem[(size_t)m * CO + col];
        } else {
            const int cc = col - CO;
            x[i] = attended[(size_t)((cc >> 7) * MS + m) * HDIM + (cc & 127)];
        }
    }
    float s = 0.f, sq = 0.f;
#pragma unroll
    for (int i = 0; i < 8; ++i) { s += x[i]; sq += x[i] * x[i]; }
    block_reduce2(s, sq);
    const float mu = s * (1.0f / IN2);
    const float var = sq * (1.0f / IN2) - mu * mu;
    const float rs = rsqrtf(var + 1e-5f);
#pragma unroll
    for (int i = 0; i < 8; ++i) {
        const int col = i * 256 + tid;
        h1[(size_t)m * IN2 + col] = (x[i] - mu) * rs * g[col] + bb[col];
    }
}

// ---------------- final LN over rows of 1024 -> dyn output ----
__global__ __launch_bounds__(256) void ln2_kernel(
    const float* __restrict__ in, const float* __restrict__ g,
    const float* __restrict__ bb, float* __restrict__ out)
{
    const int m = blockIdx.x, tid = threadIdx.x;
    float x[4];
#pragma unroll
    for (int i = 0; i < 4; ++i) x[i] = in[(size_t)m * CO + i * 256 + tid];
    float s = 0.f, sq = 0.f;
#pragma unroll
    for (int i = 0; i < 4; ++i) { s += x[i]; sq += x[i] * x[i]; }
    block_reduce2(s, sq);
    const float mu = s * (1.0f / CO);
    const float var = sq * (1.0f / CO) - mu * mu;
    const float rs = rsqrtf(var + 1e-5f);
#pragma unroll
    for (int i = 0; i < 4; ++i) {
        const int col = i * 256 + tid;
        out[(size_t)m * CO + col] = (x[i] - mu) * rs * g[col] + bb[col];
    }
}

// ---------------- load_fraction[m] = sum_h counts[h][m] / 8 ----
__global__ __launch_bounds__(256) void lf_kernel(
    const int* __restrict__ counts, float* __restrict__ out)
{
    const int m = threadIdx.x;
    float s = 0.f;
#pragma unroll
    for (int h = 0; h < NH; ++h) s += (float)counts[h * MS + m];
    out[m] = s * 0.125f;
}

extern "C" void kernel_launch(void* const* d_in, const int* in_sizes, int n_in,
                              void* d_out, int out_size, void* d_ws, size_t ws_size,
                              hipStream_t stream)
{
    const float* bqry = (const float*)d_in[0];   // [32768][2048]
    const float* memb = (const float*)d_in[1];   // [256][1024]
    const float* Wq   = (const float*)d_in[2];   // [2048][1024]
    const float* bq   = (const float*)d_in[3];
    const float* Ws1  = (const float*)d_in[4];   // [1024][4096]
    const float* bs1  = (const float*)d_in[5];
    const float* Ws2  = (const float*)d_in[6];   // [4096][1024]
    const float* bs2  = (const float*)d_in[7];
    const float* mbia = (const float*)d_in[8];   // [8,256,1]
    const float* ln1g = (const float*)d_in[9];
    const float* ln1b = (const float*)d_in[10];
    const float* Wu1  = (const float*)d_in[11];  // [2048][2048]
    const float* bu1  = (const float*)d_in[12];
    const float* Wu2  = (const float*)d_in[13];  // [2048][1024]
    const float* bu2  = (const float*)d_in[14];
    const float* lnog = (const float*)d_in[15];
    const float* lnob = (const float*)d_in[16];

    float* out = (float*)d_out;
    float* dyn_out = out;                                   // 256*1024
    float* sc1 = out + (size_t)MS * CO;                     // scores_div
    float* sc2 = sc1 + (size_t)NH * MS * TOK;               // gate_logits
    float* lf  = sc2 + (size_t)NH * MS * TOK;               // [256]

    char* wsp = (char*)d_ws;
    auto alloc = [&](size_t bytes) {
        char* p = wsp;
        wsp += (bytes + 255) & ~(size_t)255;
        return p;
    };
    // Aliased region: bqh/bql (268 MB) die after the kv GEMM; kvT + gat are
    // laid exactly over them (written strictly afterwards).
    char* region = alloc(2 * (size_t)TOK * DM * 2);                    // 268 MB
    unsigned short* bqh  = (unsigned short*)region;
    unsigned short* bql  = bqh + (size_t)TOK * DM;
    unsigned short* kvTh = (unsigned short*)region;                    // alias
    unsigned short* kvTl = kvTh + (size_t)CO * TOK;
    unsigned short* gat  = kvTl + (size_t)CO * TOK;                    // 134 MB

    unsigned short* kvh  = (unsigned short*)alloc((size_t)TOK * CO * 2);
    unsigned short* kvl  = (unsigned short*)alloc((size_t)TOK * CO * 2);
    float* part  = (float*)alloc((size_t)SKC * NH * MS * HDIM * 4);    // 34 MB
    float* partm = (float*)alloc((size_t)8 * MS * ITR * 4 / 2);        // 16.8 MB
    unsigned short* WqTh  = (unsigned short*)alloc((size_t)CO * DM * 2);
    unsigned short* WqTl  = (unsigned short*)alloc((size_t)CO * DM * 2);
    unsigned short* Ws1Th = (unsigned short*)alloc((size_t)ITR * CO * 2);
    unsigned short* Ws1Tl = (unsigned short*)alloc((size_t)ITR * CO * 2);
    unsigned short* Ws2Th = (unsigned short*)alloc((size_t)CO * ITR * 2);
    unsigned short* Ws2Tl = (unsigned short*)alloc((size_t)CO * ITR * 2);
    unsigned short* Wu1Th = (unsigned short*)alloc((size_t)IN2 * IN2 * 2);
    unsigned short* Wu1Tl = (unsigned short*)alloc((size_t)IN2 * IN2 * 2);
    unsigned short* Wu2Th = (unsigned short*)alloc((size_t)CO * IN2 * 2);
    unsigned short* Wu2Tl = (unsigned short*)alloc((size_t)CO * IN2 * 2);
    unsigned short* mh  = (unsigned short*)alloc((size_t)MS * CO * 2);
    unsigned short* ml  = (unsigned short*)alloc((size_t)MS * CO * 2);
    unsigned short* hqh = (unsigned short*)alloc((size_t)MS * ITR * 2);
    unsigned short* hql = (unsigned short*)alloc((size_t)MS * ITR * 2);
    unsigned short* qsh = (unsigned short*)alloc((size_t)MS * CO * 2);
    unsigned short* qsl = (unsigned short*)alloc((size_t)MS * CO * 2);
    unsigned short* h1h = (unsigned short*)alloc((size_t)MS * IN2 * 2);
    unsigned short* h1l = (unsigned short*)alloc((size_t)MS * IN2 * 2);
    unsigned short* huh = (unsigned short*)alloc((size_t)MS * IN2 * 2);
    unsigned short* hul = (unsigned short*)alloc((size_t)MS * IN2 * 2);
    float* h1  = (float*)alloc((size_t)MS * IN2 * 4);
    float* h2  = (float*)alloc((size_t)MS * CO * 4);
    float* att = (float*)alloc((size_t)NH * MS * HDIM * 4);
    int*  counts = (int*)alloc((size_t)NH * MS * 4);

    const dim3 blk(256);

    // --- input splits & weight transposes ---
    split4_kernel<<<dim3(TOK * DM / 4 / 256), blk, 0, stream>>>(bqry, bqh, bql, TOK * DM / 4);
    split4_kernel<<<dim3(MS * CO / 4 / 256), blk, 0, stream>>>(memb, mh, ml, MS * CO / 4);
    wtsplit_kernel<<<dim3(CO / 32, DM / 32), blk, 0, stream>>>(Wq, WqTh, WqTl, DM, CO);
    wtsplit_kernel<<<dim3(ITR / 32, CO / 32), blk, 0, stream>>>(Ws1, Ws1Th, Ws1Tl, CO, ITR);
    wtsplit_kernel<<<dim3(CO / 32, ITR / 32), blk, 0, stream>>>(Ws2, Ws2Th, Ws2Tl, ITR, CO);
    wtsplit_kernel<<<dim3(IN2 / 32, IN2 / 32), blk, 0, stream>>>(Wu1, Wu1Th, Wu1Tl, IN2, IN2);
    wtsplit_kernel<<<dim3(CO / 32, IN2 / 32), blk, 0, stream>>>(Wu2, Wu2Th, Wu2Tl, IN2, CO);

    // --- q_slots MLP: relu(mem@Ws1+bs1)@Ws2+bs2 -> qsh/qsl (split-K) ---
    mfma64<4, 0><<<dim3(ITR / 128, MS / 128, 4), blk, 0, stream>>>(
        mh, ml, Ws1Th, Ws1Tl, CO, CO, ITR, 4, 256, nullptr,
        partm, nullptr, nullptr, nullptr);
    finish_kernel<true, 0><<<dim3(MS * ITR / 4 / 256), blk, 0, stream>>>(
        partm, bs1, ITR, 4, hqh, hql, nullptr);
    mfma64<4, 0><<<dim3(CO / 128, MS / 128, 8), blk, 0, stream>>>(
        hqh, hql, Ws2Th, Ws2Tl, ITR, ITR, CO, 8, 512, nullptr,
        partm, nullptr, nullptr, nullptr);
    finish_kernel<false, 0><<<dim3(MS * CO / 4 / 256), blk, 0, stream>>>(
        partm, bs2, CO, 8, qsh, qsl, nullptr);

    // --- kv = flat@Wq+bq (XCD-grouped 1-D grid) ---
    mfma64<0, 1><<<dim3((CO / 128) * (TOK / 128), 1, 1), blk, 0, stream>>>(
        bqh, bql, WqTh, WqTl, DM, DM, CO, DM / 64, 0, bq,
        nullptr, nullptr, kvh, kvl);

    // --- kv transpose (overwrites dead bqh region) ---
    kvt_kernel<<<dim3(TOK / 64, CO / 64), blk, 0, stream>>>(kvh, kvl, kvTh, kvTl);

    // --- zero gating + counts (gat overwrites dead bql region) ---
    hipMemsetAsync(gat, 0, (size_t)NH * MS * TOK * 2, stream);
    hipMemsetAsync(counts, 0, (size_t)NH * MS * 4, stream);

    // --- scores (dual fp32 write; XCD-paired 1-D grid) ---
    mfma64<1, 2><<<dim3((MS / 128) * (TOK / 128) * NH, 1, 1), blk, 0, stream>>>(
        qsh, qsl, kvh, kvl, CO, CO, TOK, HDIM / 64, HDIM, mbia,
        sc1, sc2, nullptr, nullptr);

    // --- top-k -> gating matrix + counts ---
    topk_gating_kernel<<<dim3(TOK / 256, NH), blk, 0, stream>>>(sc2, gat, counts);

    // --- attended = gating @ kv (split-K MFMA) ---
    gather_gemm<<<dim3(SKC, 2, NH), blk, 0, stream>>>(gat, kvTh, kvTl, part);
    red_kernel<<<dim3(NH * MS * HDIM / 256), blk, 0, stream>>>(part, att);

    // --- update MLP (split-K) ---
    ln1_kernel<<<dim3(MS), blk, 0, stream>>>(memb, att, ln1g, ln1b, h1);
    split4_kernel<<<dim3(MS * IN2 / 4 / 256), blk, 0, stream>>>(h1, h1h, h1l, MS * IN2 / 4);
    mfma64<4, 0><<<dim3(IN2 / 128, MS / 128, 8), blk, 0, stream>>>(
        h1h, h1l, Wu1Th, Wu1Tl, IN2, IN2, IN2, 4, 256, nullptr,
        partm, nullptr, nullptr, nullptr);
    finish_kernel<true, 0><<<dim3(MS * IN2 / 4 / 256), blk, 0, stream>>>(
        partm, bu1, IN2, 8, huh, hul, nullptr);
    mfma64<4, 0><<<dim3(CO / 128, MS / 128, 8), blk, 0, stream>>>(
        huh, hul, Wu2Th, Wu2Tl, IN2, IN2, CO, 4, 256, nullptr,
        partm, nullptr, nullptr, nullptr);
    finish_kernel<false, 1><<<dim3(MS * CO / 4 / 256), blk, 0, stream>>>(
        partm, bu2, CO, 8, nullptr, nullptr, h2);
    ln2_kernel<<<dim3(MS), blk, 0, stream>>>(h2, lnog, lnob, dyn_out);

    lf_kernel<<<1, blk, 0, stream>>>(counts, lf);
}